// Round 7
// baseline (2888.119 us; speedup 1.0000x reference)
//
#include <hip/hip_runtime.h>

#define HF 128
#define WF 128
#define KANC 9
#define NANC (HF*WF*KANC)      // 147456
#define NSORT 262144
#define TOPN 6000
#define NWORDS 94              // ceil(6000/64)
#define NOUT 2000
#define OFF_CLS 8000
#define OFF_REG 302912
#define NCAND 8192
#define NBCAP 2048

typedef unsigned long long u64;
typedef double d4 __attribute__((ext_vector_type(4)));

__global__ __launch_bounds__(256) void zero2_k(double* p1, int n1,
                                               double* p2, int n2) {
  int i = blockIdx.x * 256 + threadIdx.x;
  if (i < n1) p1[i] = 0.0;
  else if (i - n1 < n2) p2[i - n1] = 0.0;
}

// conv3_w [oc][ic][kh][kw] -> wt [tap][ic][oc], LDS-tiled transpose.
// Block: 64 oc x 8 ic (x 9 taps). Reads 288B-contiguous rows; writes 256B
// coalesced runs. Grid 512 blocks.
__global__ __launch_bounds__(256) void wtrans_k(const float* __restrict__ w,
                                                float* __restrict__ wt) {
  __shared__ float ld[64 * 73];
  int t = threadIdx.x;
  int ocg = blockIdx.x & 7, icg = blockIdx.x >> 3;
  int oc0 = ocg << 6, ic0 = icg << 3;
  #pragma unroll
  for (int rep = 0; rep < 18; ++rep) {
    int idx = rep * 256 + t;            // 0..4607
    int row = idx / 72, col = idx - row * 72;
    ld[row * 73 + col] = w[(size_t)(oc0 + row) * 4608 + ic0 * 9 + col];
  }
  __syncthreads();
  #pragma unroll
  for (int rep = 0; rep < 18; ++rep) {
    int idx = rep * 256 + t;
    int pair = idx >> 6, oc = idx & 63; // pair: 0..71 = ic*9+tap? order below
    int tap = pair % 9, ic = pair / 9;
    wt[(size_t)tap * 262144 + (size_t)(ic0 + ic) * 512 + oc0 + oc] =
        ld[oc * 73 + ic * 9 + tap];
  }
}

// ---------------------------------------------------------------------------
// conv3x3(512->512) as fp64-MFMA GEMM, heads fused in epilogue.
// 48KB LDS (XOR-swizzled, no pad) -> 3 blocks/CU; single barrier per K-chunk.
// D-fragment layout PROBED at runtime (verified R4/R5/R6).
// ---------------------------------------------------------------------------
#define BKC 32
#define NCHUNK 144

__global__ __launch_bounds__(256, 3) void conv_mfma_k(
    const float* __restrict__ feat, const float* __restrict__ wt,
    const float* __restrict__ conv_b, const float* __restrict__ cls_w,
    const float* __restrict__ reg_w, double* __restrict__ predacc)
{
  __shared__ __align__(16) char smraw[49152];
  float* AsB = (float*)smraw;                    // [2][32*64]
  float* BsB = (float*)(smraw + 2 * 32 * 64 * 4);// [2][32*128]
  int tid = threadIdx.x;
  int bid = blockIdx.x;
  int pt = bid & 255, ot = bid >> 8;
  int h = pt >> 1, w0 = (pt & 1) << 6;
  int oc0 = ot << 7;
  int wv = tid >> 6, l = tid & 63;
  int wr = wv >> 1, wc = wv & 1;
  int lg = l >> 4, lr = l & 15;

  // --- probe the D fragment layout (row/col per accumulator reg) ---
  int rmap[4], cmap[4];
  {
    d4 z = (d4)0.0;
    double apr = (lg == 0) ? (double)lr : 0.0;
    double bpr = (lg == 0) ? 1.0 : 0.0;
    d4 dr = __builtin_amdgcn_mfma_f64_16x16x4f64(apr, bpr, z, 0, 0, 0);
    double apc = (lg == 0) ? 1.0 : 0.0;
    double bpc = (lg == 0) ? (double)lr : 0.0;
    d4 dc = __builtin_amdgcn_mfma_f64_16x16x4f64(apc, bpc, z, 0, 0, 0);
    #pragma unroll
    for (int r = 0; r < 4; ++r) { rmap[r] = (int)dr[r]; cmap[r] = (int)dc[r]; }
  }

  d4 acc[2][4];
  #pragma unroll
  for (int t = 0; t < 2; ++t)
    #pragma unroll
    for (int u = 0; u < 4; ++u) acc[t][u] = (d4)0.0;

  float4 areg[2];
  float4 breg[4];

  auto gloadA = [&](int c) {
    int tap = c >> 4, ic0 = (c & 15) << 5;
    int kh = tap / 3 - 1, kw = tap % 3 - 1;
    int hp = h + kh;
    bool okh = ((unsigned)hp < 128u);
    #pragma unroll
    for (int i = 0; i < 2; ++i) {
      int q = tid + (i << 8);
      int r = q >> 4, c0 = (q & 15) << 2;
      float v0 = 0.f, v1 = 0.f, v2 = 0.f, v3 = 0.f;
      const float* src = &feat[((ic0 + r) << 14) + (hp << 7)];
      int wp = w0 + c0 + kw;
      if (okh) {
        if ((unsigned)(wp + 0) < 128u) v0 = src[wp + 0];
        if ((unsigned)(wp + 1) < 128u) v1 = src[wp + 1];
        if ((unsigned)(wp + 2) < 128u) v2 = src[wp + 2];
        if ((unsigned)(wp + 3) < 128u) v3 = src[wp + 3];
      }
      areg[i] = make_float4(v0, v1, v2, v3);
    }
  };
  auto gloadB = [&](int c) {
    #pragma unroll
    for (int i = 0; i < 4; ++i) {
      int q = tid + (i << 8);
      int r = q >> 5, j = q & 31;
      breg[i] = *(const float4*)&wt[(size_t)((c << 5) + r) * 512 + oc0 + (j << 2)];
    }
  };
  // XOR swizzle: col ^= (row&1)<<4 (16-float granule) -> 2-way bank reads
  auto dswrite = [&](int buf) {
    float* A = AsB + buf * (32 * 64);
    float* B = BsB + buf * (32 * 128);
    #pragma unroll
    for (int i = 0; i < 2; ++i) {
      int q = tid + (i << 8);
      int r = q >> 4, c0 = (q & 15) << 2;
      *(float4*)&A[(r << 6) + (c0 ^ ((r & 1) << 4))] = areg[i];
    }
    #pragma unroll
    for (int i = 0; i < 4; ++i) {
      int q = tid + (i << 8);
      int r = q >> 5, c0 = (q & 31) << 2;
      *(float4*)&B[(r << 7) + (c0 ^ ((r & 1) << 4))] = breg[i];
    }
  };
  auto compute = [&](int buf) {
    const float* A = AsB + buf * (32 * 64);
    const float* B = BsB + buf * (32 * 128);
    #pragma unroll
    for (int k4 = 0; k4 < BKC; k4 += 4) {
      int krow = k4 + lg;
      int sw = (krow & 1) << 4;
      double a0 = (double)A[(krow << 6) + (((wr << 5) + lr) ^ sw)];
      double a1 = (double)A[(krow << 6) + (((wr << 5) + 16 + lr) ^ sw)];
      double b0 = (double)B[(krow << 7) + (((wc << 6) + lr) ^ sw)];
      double b1 = (double)B[(krow << 7) + (((wc << 6) + 16 + lr) ^ sw)];
      double b2 = (double)B[(krow << 7) + (((wc << 6) + 32 + lr) ^ sw)];
      double b3 = (double)B[(krow << 7) + (((wc << 6) + 48 + lr) ^ sw)];
      acc[0][0] = __builtin_amdgcn_mfma_f64_16x16x4f64(a0, b0, acc[0][0], 0, 0, 0);
      acc[0][1] = __builtin_amdgcn_mfma_f64_16x16x4f64(a0, b1, acc[0][1], 0, 0, 0);
      acc[0][2] = __builtin_amdgcn_mfma_f64_16x16x4f64(a0, b2, acc[0][2], 0, 0, 0);
      acc[0][3] = __builtin_amdgcn_mfma_f64_16x16x4f64(a0, b3, acc[0][3], 0, 0, 0);
      acc[1][0] = __builtin_amdgcn_mfma_f64_16x16x4f64(a1, b0, acc[1][0], 0, 0, 0);
      acc[1][1] = __builtin_amdgcn_mfma_f64_16x16x4f64(a1, b1, acc[1][1], 0, 0, 0);
      acc[1][2] = __builtin_amdgcn_mfma_f64_16x16x4f64(a1, b2, acc[1][2], 0, 0, 0);
      acc[1][3] = __builtin_amdgcn_mfma_f64_16x16x4f64(a1, b3, acc[1][3], 0, 0, 0);
    }
  };

  // prologue + single-barrier double-buffered K loop
  gloadA(0);
  gloadB(0);
  dswrite(0);
  for (int c = 0; c < NCHUNK; ++c) {
    __syncthreads();                 // buf[c&1] ready; buf[(c+1)&1] free
    if (c + 1 < NCHUNK) {
      gloadA(c + 1);
      gloadB(c + 1);
    }
    compute(c & 1);
    if (c + 1 < NCHUNK) dswrite((c + 1) & 1);
  }

  // -------- epilogue: bias+relu -> xs (fp64), fused head dots, atomics ------
  double* xs = (double*)smraw;                 // [64][65] doubles = 33280 B
  float* hwS = (float*)(smraw + 64 * 65 * 8);  // [54][64] floats  = 13824 B
  double sacc[14];
  #pragma unroll
  for (int it = 0; it < 14; ++it) sacc[it] = 0.0;

  #pragma unroll
  for (int hh = 0; hh < 2; ++hh) {
    __syncthreads();   // all compute reads done / prev half's dots done
    for (int e = tid; e < 54 * 64; e += 256) {
      int o = e >> 6, j = e & 63;
      int oc = oc0 + (hh << 6) + j;
      hwS[e] = (o < 18) ? cls_w[(o << 9) + oc] : reg_w[((o - 18) << 9) + oc];
    }
    if (wc == hh) {
      #pragma unroll
      for (int t = 0; t < 2; ++t) {
        #pragma unroll
        for (int u = 0; u < 4; ++u) {
          #pragma unroll
          for (int r = 0; r < 4; ++r) {
            int ocl = (u << 4) + cmap[r];
            int pxl = (wr << 5) + (t << 4) + rmap[r];
            double v = acc[t][u][r] + (double)conv_b[oc0 + (hh << 6) + ocl];
            xs[pxl * 65 + ocl] = (v > 0.0) ? v : 0.0;
          }
        }
      }
    }
    __syncthreads();
    #pragma unroll
    for (int it = 0; it < 14; ++it) {
      int e = tid + (it << 8);
      if (e < 54 * 64) {
        int o = e >> 6, px = e & 63;
        const double* xr = &xs[px * 65];
        const float* hr = &hwS[o << 6];
        double s = 0.0;
        #pragma unroll
        for (int j = 0; j < 64; ++j) s += xr[j] * (double)hr[j];
        sacc[it] += s;
      }
    }
  }
  int pixbase = (h << 7) + w0;
  #pragma unroll
  for (int it = 0; it < 14; ++it) {
    int e = tid + (it << 8);
    if (e < 54 * 64) {
      int o = e >> 6, px = e & 63;
      atomicAdd(&predacc[(size_t)(pixbase + px) * 54 + o], sacc[it]);
    }
  }
}

// --------- verification: recompute x for 4 probe pixels (ic-split) ----------
__global__ __launch_bounds__(256) void chk_x_k(
    const float* __restrict__ feat, const float* __restrict__ c3w,
    double* __restrict__ xraw)
{
  int task = blockIdx.x * 256 + threadIdx.x;  // 16384 = 4px * 512oc * 8icg
  int pi = task >> 12;
  int oc = (task >> 3) & 511;
  int icg = task & 7;
  const int pixs[4] = {0, 5437, 10240, 16383};
  int pix = pixs[pi];
  int h = pix >> 7, w = pix & 127;
  double s = 0.0;
  for (int ic = icg * 64; ic < icg * 64 + 64; ++ic) {
    const float* f = &feat[ic << 14];
    const float* wp = &c3w[(size_t)(oc * 512 + ic) * 9];
    #pragma unroll
    for (int kh = -1; kh <= 1; ++kh) {
      int hp = h + kh;
      if ((unsigned)hp >= 128u) continue;
      #pragma unroll
      for (int kw = -1; kw <= 1; ++kw) {
        int wq = w + kw;
        if ((unsigned)wq >= 128u) continue;
        s += (double)f[(hp << 7) + wq] * (double)wp[(kh + 1) * 3 + (kw + 1)];
      }
    }
  }
  atomicAdd(&xraw[(pi << 9) + oc], s);
}

__global__ __launch_bounds__(256) void chk_cmp_k(
    const double* __restrict__ xraw, const float* __restrict__ c3b,
    const float* __restrict__ cls_w, const float* __restrict__ reg_w,
    const double* __restrict__ predacc, double* flagd)
{
  int t = threadIdx.x;
  if (t >= 216) return;
  int pi = t / 54, o = t - pi * 54;
  const int pixs[4] = {0, 5437, 10240, 16383};
  const float* wrow = (o < 18) ? &cls_w[o << 9] : &reg_w[(o - 18) << 9];
  const double* xr = &xraw[pi << 9];
  double s = 0.0;
  for (int j = 0; j < 512; ++j) {
    double x = xr[j] + (double)c3b[j];
    x = x > 0.0 ? x : 0.0;
    s += x * (double)wrow[j];
  }
  double got = predacc[(size_t)pixs[pi] * 54 + o];
  if (fabs(got - s) > 1e-6) *flagd = 1.0;
}

__global__ __launch_bounds__(256) void rezero_k(const double* __restrict__ flagd,
                                                double* p, int n) {
  if (*flagd == 0.0) return;
  int i = blockIdx.x * 256 + threadIdx.x;
  if (i < n) p[i] = 0.0;
}

// R1-proven VALU conv+heads fallback, gated on flag
__global__ __launch_bounds__(256) void conv_fb_k(
    const double* __restrict__ flagd,
    const float* __restrict__ feat, const float* __restrict__ wt,
    const float* __restrict__ conv_b, const float* __restrict__ cls_w,
    const float* __restrict__ reg_w, double* __restrict__ predacc)
{
  if (*flagd == 0.0) return;
  __shared__ __align__(16) char smraw[47104];
  double* As = (double*)smraw;
  double* Bs = As + 2048;
  int tid = threadIdx.x;
  int bid = blockIdx.x;
  int pt = bid & 255, ot = bid >> 8;
  int h = pt >> 1, w0 = (pt & 1) << 6;
  int oc0 = ot << 6;
  int tx = tid & 15, ty = tid >> 4;

  double acc[4][4];
  #pragma unroll
  for (int i = 0; i < 4; ++i)
    #pragma unroll
    for (int j = 0; j < 4; ++j) acc[i][j] = 0.0;

  for (int tap = 0; tap < 9; ++tap) {
    int kh = tap / 3 - 1, kw = tap % 3 - 1;
    int hp = h + kh;
    bool okh = (hp >= 0) && (hp < HF);
    for (int icc = 0; icc < 16; ++icc) {
      int ic0 = icc << 5;
      __syncthreads();
      #pragma unroll
      for (int i = 0; i < 8; ++i) {
        int e = tid + (i << 8);
        int icl = e >> 6;
        int lx = e & 63;
        int wp = w0 + lx + kw;
        float v = 0.0f;
        if (okh && wp >= 0 && wp < WF)
          v = feat[((ic0 + icl) << 14) + (hp << 7) + wp];
        As[(icl << 6) + lx] = (double)v;
        Bs[(icl << 6) + lx] =
            (double)wt[((((tap << 9) + ic0 + icl)) << 9) + oc0 + lx];
      }
      __syncthreads();
      #pragma unroll
      for (int k = 0; k < 32; ++k) {
        const double* ar = &As[(k << 6) + (ty << 2)];
        const double* br = &Bs[(k << 6) + (tx << 2)];
        double a0 = ar[0], a1 = ar[1], a2 = ar[2], a3 = ar[3];
        double b0 = br[0], b1 = br[1], b2 = br[2], b3 = br[3];
        acc[0][0] += a0 * b0; acc[0][1] += a0 * b1; acc[0][2] += a0 * b2; acc[0][3] += a0 * b3;
        acc[1][0] += a1 * b0; acc[1][1] += a1 * b1; acc[1][2] += a1 * b2; acc[1][3] += a1 * b3;
        acc[2][0] += a2 * b0; acc[2][1] += a2 * b1; acc[2][2] += a2 * b2; acc[2][3] += a2 * b3;
        acc[3][0] += a3 * b0; acc[3][1] += a3 * b1; acc[3][2] += a3 * b2; acc[3][3] += a3 * b3;
      }
    }
  }
  __syncthreads();
  double* xs = (double*)smraw;
  float* hwS = (float*)(smraw + 64 * 65 * 8);
  #pragma unroll
  for (int i = 0; i < 4; ++i) {
    int px = (ty << 2) + i;
    #pragma unroll
    for (int j = 0; j < 4; ++j) {
      int oc = (tx << 2) + j;
      double v = acc[i][j] + (double)conv_b[oc0 + oc];
      xs[px * 65 + oc] = v > 0.0 ? v : 0.0;
    }
  }
  for (int e = tid; e < 54 * 64; e += 256) {
    int o = e >> 6, ocl = e & 63;
    hwS[e] = (o < 18) ? cls_w[(o << 9) + oc0 + ocl]
                      : reg_w[((o - 18) << 9) + oc0 + ocl];
  }
  __syncthreads();
  int pixbase = (h << 7) + w0;
  for (int e = tid; e < 54 * 64; e += 256) {
    int px = e & 63, o = e >> 6;
    const double* xr = &xs[px * 65];
    const float* hr = &hwS[o << 6];
    double s = 0.0;
    #pragma unroll
    for (int j = 0; j < 64; ++j) s += xr[j] * (double)hr[j];
    atomicAdd(&predacc[(pixbase + px) * 54 + o], s);
  }
}

// per-anchor: heads bias, outputs, anchors, make_roi, score, sort entry
__global__ __launch_bounds__(256) void anchor_k(
    const double* __restrict__ predacc, const float* __restrict__ cls_b,
    const float* __restrict__ reg_b, float* __restrict__ out,
    double* __restrict__ roi_all, double* __restrict__ scores_d,
    ulonglong2* __restrict__ sortb)
{
  #pragma clang fp contract(off)
  int a = blockIdx.x * 256 + threadIdx.x;
  if (a >= NSORT) return;
  if (a >= NANC) {
    sortb[a] = make_ulonglong2(0xFFF0000000000000ULL, 0xFFFFFFFFULL);
    return;
  }
  int pix = a / 9;
  int k = a - pix * 9;
  int h = pix >> 7, wq = pix & 127;
  const double* pa = &predacc[pix * 54];
  double c0 = pa[2 * k] + (double)cls_b[2 * k];
  double c1 = pa[2 * k + 1] + (double)cls_b[2 * k + 1];
  double d0 = pa[18 + 4 * k + 0] + (double)reg_b[4 * k + 0];
  double d1 = pa[18 + 4 * k + 1] + (double)reg_b[4 * k + 1];
  double d2 = pa[18 + 4 * k + 2] + (double)reg_b[4 * k + 2];
  double d3 = pa[18 + 4 * k + 3] + (double)reg_b[4 * k + 3];
  out[OFF_CLS + a * 2 + 0] = (float)c0;
  out[OFF_CLS + a * 2 + 1] = (float)c1;
  out[OFF_REG + a * 4 + 0] = (float)d0;
  out[OFF_REG + a * 4 + 1] = (float)d1;
  out[OFF_REG + a * 4 + 2] = (float)d2;
  out[OFF_REG + a * 4 + 3] = (float)d3;
  int ir = k / 3, is = k - ir * 3;
  double ratio = (ir == 0) ? 0.5 : (ir == 1 ? 1.0 : 2.0);
  double asz = (is == 0) ? 8.0 : (is == 1 ? 16.0 : 32.0);
  double sq = sqrt(ratio);
  double wa = (16.0 * asz) / sq;
  double ha = (16.0 * asz) * sq;
  double cx = (h + 0.5) * 16.0;
  double cy = (wq + 0.5) * 16.0;
  double A0 = (double)(float)rint(cx - wa * 0.5);
  double A1 = (double)(float)rint(cy - ha * 0.5);
  double A2 = (double)(float)rint(cx + wa * 0.5);
  double A3 = (double)(float)rint(cy + ha * 0.5);
  double aw = A2 - A0, ah = A3 - A1;
  double acx = A0 + aw * 0.5, acy = A1 + ah * 0.5;
  double ccx = d0 * aw + acx;
  double ccy = d1 * ah + acy;
  double wr = exp(d2) * aw;
  double hh = exp(d3) * ah;
  double r0 = ccx - wr * 0.5;
  double r1 = ccy - hh * 0.5;
  double r2 = ccx + wr * 0.5;
  double r3 = ccy + hh * 0.5;
  r0 = fmax(r0, 0.0); r1 = fmax(r1, 0.0); r2 = fmax(r2, 0.0); r3 = fmax(r3, 0.0);
  r3 = (r3 > 2048.0) ? 2047.0 : r3;
  r2 = (r2 > 2048.0) ? 2047.0 : r2;
  bool valid = ((r2 - r0) > 16.0) && ((r3 - r1) > 16.0);
  double score = valid ? c1 : -__builtin_huge_val();
  roi_all[a * 4 + 0] = r0;
  roi_all[a * 4 + 1] = r1;
  roi_all[a * 4 + 2] = r2;
  roi_all[a * 4 + 3] = r3;
  scores_d[a] = score;
  u64 u = (u64)__double_as_longlong(score);
  u64 m = (u >> 63) ? ~u : (u | 0x8000000000000000ULL);
  sortb[a] = make_ulonglong2(~m, (u64)a);
}

// ------------------------- radix-select top-6000 ----------------------------
__global__ __launch_bounds__(1024) void init_sel_k(unsigned* hist, u64* selp,
                                                   unsigned* cnt) {
  int t = blockIdx.x * 1024 + threadIdx.x;
  if (t < 2048) hist[t] = 0;
  if (t == 0) { selp[0] = 0; selp[1] = 0; cnt[0] = 0; cnt[1] = 0; }
}

__global__ __launch_bounds__(1024) void hist_k(const ulonglong2* __restrict__ sortb,
                                               unsigned* __restrict__ hist,
                                               const u64* __restrict__ selp,
                                               int pass) {
  __shared__ unsigned h[2048];
  int t = threadIdx.x;
  h[t] = 0; h[t + 1024] = 0;
  __syncthreads();
  const int SH[3] = {53, 42, 31};
  const u64 PM[3] = {0ULL, 0xFFE0000000000000ULL, 0xFFFFFC0000000000ULL};
  u64 pfx = selp[0];
  u64 pm = PM[pass];
  int sh = SH[pass];
  for (int e = blockIdx.x * 1024 + t; e < NSORT; e += gridDim.x * 1024) {
    u64 k = sortb[e].x;
    if ((k & pm) == pfx)
      atomicAdd(&h[(unsigned)((k >> sh) & 2047)], 1u);
  }
  __syncthreads();
  if (h[t]) atomicAdd(&hist[t], h[t]);
  if (h[t + 1024]) atomicAdd(&hist[t + 1024], h[t + 1024]);
}

__global__ __launch_bounds__(1024) void scan_k(unsigned* hist, u64* selp, int pass) {
  __shared__ unsigned h[2048];
  int t = threadIdx.x;
  h[t] = hist[t]; h[t + 1024] = hist[t + 1024];
  hist[t] = 0; hist[t + 1024] = 0;
  __syncthreads();
  if (t == 0) {
    const int SH[3] = {53, 42, 31};
    u64 cum = selp[1];
    u64 pfx = selp[0];
    int b = 0;
    for (; b < 2047; ++b) {
      if (cum + h[b] >= (u64)TOPN) break;
      cum += h[b];
    }
    selp[0] = pfx | ((u64)b << SH[pass]);
    selp[1] = cum;
  }
}

__global__ __launch_bounds__(1024) void compact_k(
    const ulonglong2* __restrict__ sortb, const u64* __restrict__ selp,
    ulonglong2* __restrict__ cand, ulonglong2* __restrict__ bcand,
    unsigned* __restrict__ cnt) {
  u64 pfx = selp[0];
  const u64 M33 = 0xFFFFFFFF80000000ULL;
  for (int e = blockIdx.x * 1024 + threadIdx.x; e < NSORT; e += gridDim.x * 1024) {
    ulonglong2 v = sortb[e];
    u64 top = v.x & M33;
    if (top < pfx) {
      unsigned p = atomicAdd(&cnt[0], 1u);
      if (p < NCAND) cand[p] = v;
    } else if (top == pfx) {
      unsigned p = atomicAdd(&cnt[1], 1u);
      if (p < NBCAP) bcand[p] = v;
    }
  }
}

__global__ __launch_bounds__(1024) void fill_k(ulonglong2* cand,
                                               const ulonglong2* __restrict__ bcand,
                                               const unsigned* __restrict__ cnt) {
  int t = blockIdx.x * 1024 + threadIdx.x;
  unsigned ci = cnt[0];
  unsigned cb = cnt[1] < NBCAP ? cnt[1] : NBCAP;
  if (t >= (int)ci) {
    if (t < (int)(ci + cb)) cand[t] = bcand[t - ci];
    else if (t < NCAND) cand[t] = make_ulonglong2(~0ULL, ~0ULL);
  }
}

// ------------------- single-block LDS bitonic sort of 8192 ------------------
__device__ __forceinline__ bool sless(ulonglong2 A, ulonglong2 B) {
  return (A.x < B.x) || (A.x == B.x && A.y < B.y);
}

__global__ __launch_bounds__(1024) void sort8k_k(ulonglong2* d) {
  extern __shared__ ulonglong2 s[];   // 8192 * 16B = 128 KB dynamic LDS
  int t = threadIdx.x;
  #pragma unroll
  for (int i = 0; i < 8; ++i) s[t + (i << 10)] = d[t + (i << 10)];
  __syncthreads();
  for (int k = 2; k <= NCAND; k <<= 1) {
    for (int j = k >> 1; j >= 1; j >>= 1) {
      #pragma unroll
      for (int q = 0; q < 4; ++q) {
        int p = t + (q << 10);
        int li = ((p & ~(j - 1)) << 1) | (p & (j - 1));
        int pa = li | j;
        bool asc = ((li & k) == 0);
        ulonglong2 A = s[li], B = s[pa];
        bool sw = asc ? sless(B, A) : sless(A, B);
        if (sw) { s[li] = B; s[pa] = A; }
      }
      __syncthreads();
    }
  }
  #pragma unroll
  for (int i = 0; i < 8; ++i) d[t + (i << 10)] = s[t + (i << 10)];
}

// ----------------------------- NMS pipeline ---------------------------------
__global__ __launch_bounds__(1024) void prep_k(
    const ulonglong2* __restrict__ sorted, const double* __restrict__ roi_all,
    const double* __restrict__ scores_d, double* __restrict__ boxes,
    u64* __restrict__ removed)
{
  int t = threadIdx.x;
  for (int i = t; i < TOPN; i += 1024) {
    unsigned idx = (unsigned)sorted[i].y;
    double b0 = 0, b1 = 0, b2 = 0, b3 = 0;
    if (idx < NANC) {
      b0 = roi_all[idx * 4 + 0];
      b1 = roi_all[idx * 4 + 1];
      b2 = roi_all[idx * 4 + 2];
      b3 = roi_all[idx * 4 + 3];
    }
    boxes[i * 4 + 0] = b0; boxes[i * 4 + 1] = b1;
    boxes[i * 4 + 2] = b2; boxes[i * 4 + 3] = b3;
  }
  if (t < NWORDS) {
    u64 wdd = (t == NWORDS - 1) ? 0xFFFF000000000000ULL : 0ULL;
    for (int b = 0; b < 64; ++b) {
      int i = t * 64 + b;
      if (i >= TOPN) break;
      unsigned idx = (unsigned)sorted[i].y;
      bool dead = true;
      if (idx < NANC) dead = isinf(scores_d[idx]);
      if (dead) wdd |= (1ULL << b);
    }
    removed[t] = wdd;
  }
}

// suppression bitmask (triangular: only words w >= chunk(i) are written/read)
__global__ __launch_bounds__(256) void mask_k(const double* __restrict__ boxes,
                                              u64* __restrict__ mask) {
  #pragma clang fp contract(off)
  int gw = (blockIdx.x * 256 + threadIdx.x) >> 6;
  int lane = threadIdx.x & 63;
  int i = gw / NWORDS, wj = gw - i * NWORDS;
  if (i >= TOPN) return;
  if (wj < (i >> 6)) return;
  double ix1 = boxes[i * 4 + 0], iy1 = boxes[i * 4 + 1];
  double ix2 = boxes[i * 4 + 2], iy2 = boxes[i * 4 + 3];
  double tx1 = trunc(ix1), ty1 = trunc(iy1), tx2 = trunc(ix2), ty2 = trunc(iy2);
  double gminx = fmin(tx1, tx2), gmaxx = fmax(tx1, tx2);
  double gminy = fmin(ty1, ty2), gmaxy = fmax(ty1, ty2);
  double gw_ = trunc(ix2 - ix1), gh_ = trunc(iy2 - iy1);
  int j = wj * 64 + lane;
  bool pred = false;
  if (j < TOPN && j > i) {
    double jx1 = boxes[j * 4 + 0], jy1 = boxes[j * 4 + 1];
    double jx2 = boxes[j * 4 + 2], jy2 = boxes[j * 4 + 3];
    double aw = jx2 - jx1, ah = jy2 - jy1;
    double aminx = fmin(jx1, jx2), amaxx = fmax(jx1, jx2);
    double aminy = fmin(jy1, jy2), amaxy = fmax(jy1, jy2);
    double iw = fmin(aminx, gminx) + aw + gw_ - fmax(amaxx, gmaxx);
    iw = fmax(iw, 0.0);
    double ih = fmin(aminy, gminy) + ah + gh_ - fmax(amaxy, gmaxy);
    ih = fmax(ih, 0.0);
    double inter = iw * ih;
    double uni = aw * ah + gw_ * gh_ - inter;
    pred = (inter / uni >= 0.7);
  }
  u64 bal = __ballot(pred);
  if (lane == 0) mask[(size_t)i * NWORDS + wj] = bal;
}

// chunked greedy suppression
__global__ __launch_bounds__(1024) void nms_chunk_k(const u64* __restrict__ mask,
                                                    u64* removed_g) {
  __shared__ u64 rem[NWORDS];
  __shared__ u64 aliveSh;
  int t = threadIdx.x;
  int lane = t & 63;
  int wvid = t >> 6;
  if (t < NWORDS) rem[t] = removed_g[t];
  __syncthreads();
  for (int c = 0; c < NWORDS; ++c) {
    if (wvid == 0) {
      int i = c * 64 + lane;
      u64 diag = (i < TOPN) ? mask[(size_t)i * NWORDS + c] : 0ULL;
      u64 local = rem[c];
      #pragma unroll 1
      for (int j = 0; j < 64; ++j) {
        u64 dj = __shfl(diag, j);
        if (!((local >> j) & 1ULL)) local |= dj;
      }
      if (lane == 0) { rem[c] = local; aliveSh = ~local; }
    }
    __syncthreads();
    u64 alive = aliveSh;
    int nw = NWORDS - 1 - c;
    if (nw > 0 && alive) {
      int npairs = 64 * nw;
      for (int p = t; p < npairs; p += 1024) {
        int j = p / nw;
        int w = c + 1 + (p - j * nw);
        if ((alive >> j) & 1ULL) {
          int i = c * 64 + j;
          if (i < TOPN) {
            u64 v = mask[(size_t)i * NWORDS + w];
            if (v) atomicOr(&rem[w], v);
          }
        }
      }
    }
    __syncthreads();
  }
  if (t < NWORDS) removed_g[t] = rem[t];
}

__global__ __launch_bounds__(256) void out_k(const u64* __restrict__ removed,
                                             const double* __restrict__ boxes,
                                             float* __restrict__ out) {
  __shared__ int pref[NWORDS + 1];
  __shared__ u64 keepw[NWORDS];
  int t = threadIdx.x;
  for (int i = t; i < NOUT * 4; i += 256) out[i] = 0.0f;
  if (t < NWORDS) keepw[t] = ~removed[t];
  __syncthreads();
  if (t == 0) {
    int s = 0;
    for (int w = 0; w < NWORDS; ++w) { pref[w] = s; s += __popcll(keepw[w]); }
    pref[NWORDS] = s;
  }
  __syncthreads();
  for (int i = t; i < TOPN; i += 256) {
    u64 kw = keepw[i >> 6];
    if ((kw >> (i & 63)) & 1ULL) {
      int rank = pref[i >> 6] + __popcll(kw & ((1ULL << (i & 63)) - 1ULL));
      if (rank < NOUT) {
        out[rank * 4 + 0] = (float)boxes[i * 4 + 0];
        out[rank * 4 + 1] = (float)boxes[i * 4 + 1];
        out[rank * 4 + 2] = (float)boxes[i * 4 + 2];
        out[rank * 4 + 3] = (float)boxes[i * 4 + 3];
      }
    }
  }
}

extern "C" void kernel_launch(void* const* d_in, const int* in_sizes, int n_in,
                              void* d_out, int out_size, void* d_ws, size_t ws_size,
                              hipStream_t stream) {
  const float* feat = (const float*)d_in[0];
  const float* c3w = (const float*)d_in[1];
  const float* c3b = (const float*)d_in[2];
  const float* clw = (const float*)d_in[3];
  const float* clb = (const float*)d_in[4];
  const float* rgw = (const float*)d_in[5];
  const float* rgb = (const float*)d_in[6];
  float* out = (float*)d_out;
  char* ws = (char*)d_ws;
  size_t off = 0;
  auto alloc = [&](size_t bytes) {
    size_t o = off;
    off = (off + bytes + 255) & ~(size_t)255;
    return o;
  };
  double* predacc = (double*)(ws + alloc(16384ULL * 54 * 8));     // 7.08 MB
  double* flagd = (double*)(ws + alloc(256));                     // after predacc
  float* wt = (float*)(ws + alloc(2359296ULL * 4));               // 9.44 MB
  double* roi_all = (double*)(ws + alloc((size_t)NANC * 4 * 8));  // 4.72 MB
  double* scores_d = (double*)(ws + alloc((size_t)NANC * 8));     // 1.18 MB
  ulonglong2* sortb = (ulonglong2*)(ws + alloc((size_t)NSORT * 16)); // 4.19 MB
  double* boxes = (double*)(ws + alloc((size_t)TOPN * 4 * 8));    // 0.19 MB
  u64* mask = (u64*)(ws + alloc((size_t)TOPN * NWORDS * 8));      // 4.51 MB
  u64* removed = (u64*)(ws + alloc(NWORDS * 8));
  double* xraw = (double*)(ws + alloc(4 * 512 * 8));              // 16 KB
  unsigned* hist = (unsigned*)(ws + alloc(2048 * 4));             // 8 KB
  u64* selp = (u64*)(ws + alloc(256));
  unsigned* cntb = (unsigned*)(ws + alloc(256));
  ulonglong2* cand = (ulonglong2*)(ws + alloc((size_t)NCAND * 16));   // 128 KB
  ulonglong2* bcand = (ulonglong2*)(ws + alloc((size_t)NBCAP * 16));  // 32 KB
  (void)ws_size; (void)out_size; (void)in_sizes; (void)n_in;

  const int NPRED = 16384 * 54;
  hipLaunchKernelGGL(zero2_k, dim3((NPRED + 32 + 2048 + 255) / 256), dim3(256), 0,
                     stream, predacc, NPRED + 32, xraw, 2048);
  hipLaunchKernelGGL(wtrans_k, dim3(512), dim3(256), 0, stream, c3w, wt);
  hipLaunchKernelGGL(conv_mfma_k, dim3(1024), dim3(256), 0, stream,
                     feat, wt, c3b, clw, rgw, predacc);
  // verify MFMA result at 4 probe pixels; gated VALU fallback
  hipLaunchKernelGGL(chk_x_k, dim3(64), dim3(256), 0, stream, feat, c3w, xraw);
  hipLaunchKernelGGL(chk_cmp_k, dim3(1), dim3(256), 0, stream,
                     xraw, c3b, clw, rgw, predacc, flagd);
  hipLaunchKernelGGL(rezero_k, dim3((NPRED + 255) / 256), dim3(256), 0, stream,
                     flagd, predacc, NPRED);
  hipLaunchKernelGGL(conv_fb_k, dim3(2048), dim3(256), 0, stream,
                     flagd, feat, wt, c3b, clw, rgw, predacc);
  hipLaunchKernelGGL(anchor_k, dim3(NSORT / 256), dim3(256), 0, stream,
                     predacc, clb, rgb, out, roi_all, scores_d, sortb);
  // radix-select top-6000
  hipLaunchKernelGGL(init_sel_k, dim3(2), dim3(1024), 0, stream, hist, selp, cntb);
  for (int pass = 0; pass < 3; ++pass) {
    hipLaunchKernelGGL(hist_k, dim3(128), dim3(1024), 0, stream,
                       sortb, hist, selp, pass);
    hipLaunchKernelGGL(scan_k, dim3(1), dim3(1024), 0, stream, hist, selp, pass);
  }
  hipLaunchKernelGGL(compact_k, dim3(128), dim3(1024), 0, stream,
                     sortb, selp, cand, bcand, cntb);
  hipLaunchKernelGGL(fill_k, dim3(NCAND / 1024), dim3(1024), 0, stream,
                     cand, bcand, cntb);
  hipLaunchKernelGGL(sort8k_k, dim3(1), dim3(1024), NCAND * 16, stream, cand);
  // NMS
  hipLaunchKernelGGL(prep_k, dim3(1), dim3(1024), 0, stream,
                     cand, roi_all, scores_d, boxes, removed);
  hipLaunchKernelGGL(mask_k, dim3(TOPN * NWORDS / 4), dim3(256), 0, stream,
                     boxes, mask);
  hipLaunchKernelGGL(nms_chunk_k, dim3(1), dim3(1024), 0, stream, mask, removed);
  hipLaunchKernelGGL(out_k, dim3(1), dim3(256), 0, stream, removed, boxes, out);
}

// Round 8
// 2519.166 us; speedup vs baseline: 1.1465x; 1.1465x over previous
//
#include <hip/hip_runtime.h>

#define HF 128
#define WF 128
#define KANC 9
#define NANC (HF*WF*KANC)      // 147456
#define NSORT 262144
#define TOPN 6000
#define NWORDS 94              // ceil(6000/64)
#define NOUT 2000
#define OFF_CLS 8000
#define OFF_REG 302912
#define NCAND 8192
#define NBCAP 2048

typedef unsigned long long u64;
typedef double d4 __attribute__((ext_vector_type(4)));
typedef const __attribute__((address_space(1))) void* gas1;
typedef __attribute__((address_space(3))) void* las3;

__global__ __launch_bounds__(256) void zero2_k(double* p1, int n1,
                                               double* p2, int n2) {
  int i = blockIdx.x * 256 + threadIdx.x;
  if (i < n1) p1[i] = 0.0;
  else if (i - n1 < n2) p2[i - n1] = 0.0;
}

// conv3_w [oc][ic][kh][kw] -> wt [tap][ic][oc], LDS-tiled transpose.
__global__ __launch_bounds__(256) void wtrans_k(const float* __restrict__ w,
                                                float* __restrict__ wt) {
  __shared__ float ld[64 * 73];
  int t = threadIdx.x;
  int ocg = blockIdx.x & 7, icg = blockIdx.x >> 3;
  int oc0 = ocg << 6, ic0 = icg << 3;
  #pragma unroll
  for (int rep = 0; rep < 18; ++rep) {
    int idx = rep * 256 + t;            // 0..4607
    int row = idx / 72, col = idx - row * 72;
    ld[row * 73 + col] = w[(size_t)(oc0 + row) * 4608 + ic0 * 9 + col];
  }
  __syncthreads();
  #pragma unroll
  for (int rep = 0; rep < 18; ++rep) {
    int idx = rep * 256 + t;
    int pair = idx >> 6, oc = idx & 63;
    int tap = pair % 9, ic = pair / 9;
    wt[(size_t)tap * 262144 + (size_t)(ic0 + ic) * 512 + oc0 + oc] =
        ld[oc * 73 + ic * 9 + tap];
  }
}

// ---------------------------------------------------------------------------
// conv3x3(512->512) as fp64-MFMA GEMM, heads fused in epilogue.
// 48KB LDS (XOR-swizzled) -> 3 blocks/CU; single barrier per K-chunk.
// B-panel staged via global_load_lds (pre-swizzled source); A reg-staged.
// D-fragment layout PROBED at runtime, post-loop (verified R4-R7).
// ---------------------------------------------------------------------------
#define BKC 32
#define NCHUNK 144

__global__ __launch_bounds__(256, 3) void conv_mfma_k(
    const float* __restrict__ feat, const float* __restrict__ wt,
    const float* __restrict__ conv_b, const float* __restrict__ cls_w,
    const float* __restrict__ reg_w, double* __restrict__ predacc)
{
  __shared__ __align__(16) char smraw[49152];
  float* AsB = (float*)smraw;                    // [2][32*64]
  float* BsB = (float*)(smraw + 2 * 32 * 64 * 4);// [2][32*128]
  int tid = threadIdx.x;
  int bid = blockIdx.x;
  int pt = bid & 255, ot = bid >> 8;
  int h = pt >> 1, w0 = (pt & 1) << 6;
  int oc0 = ot << 7;
  int wv = tid >> 6, l = tid & 63;
  int wr = wv >> 1, wc = wv & 1;
  int lg = l >> 4, lr = l & 15;

  d4 acc[2][4];
  #pragma unroll
  for (int t = 0; t < 2; ++t)
    #pragma unroll
    for (int u = 0; u < 4; ++u) acc[t][u] = (d4)0.0;

  float4 areg[2];

  auto gloadA = [&](int c) {
    int tap = c >> 4, ic0 = (c & 15) << 5;
    int kh = tap / 3 - 1, kw = tap % 3 - 1;
    int hp = h + kh;
    bool okh = ((unsigned)hp < 128u);
    #pragma unroll
    for (int i = 0; i < 2; ++i) {
      int q = tid + (i << 8);
      int r = q >> 4, c0 = (q & 15) << 2;
      float v0 = 0.f, v1 = 0.f, v2 = 0.f, v3 = 0.f;
      const float* src = &feat[((ic0 + r) << 14) + (hp << 7)];
      int wp = w0 + c0 + kw;
      if (okh) {
        if ((unsigned)(wp + 0) < 128u) v0 = src[wp + 0];
        if ((unsigned)(wp + 1) < 128u) v1 = src[wp + 1];
        if ((unsigned)(wp + 2) < 128u) v2 = src[wp + 2];
        if ((unsigned)(wp + 3) < 128u) v3 = src[wp + 3];
      }
      areg[i] = make_float4(v0, v1, v2, v3);
    }
  };
  // B: direct global->LDS DMA. LDS dest is linear in q (q*16B, wave-uniform
  // base + lane*16); the XOR swizzle is applied to the GLOBAL column instead,
  // so the swizzled-read side (compute) sees the same layout as R7.
  auto gloadB_lds = [&](int c, int buf) {
    float* B = BsB + buf * (32 * 128);
    #pragma unroll
    for (int i = 0; i < 4; ++i) {
      int q = tid + (i << 8);
      int r = q >> 5, c0 = (q & 31) << 2;
      const float* src =
          &wt[(size_t)((c << 5) + r) * 512 + oc0 + (c0 ^ ((r & 1) << 4))];
      __builtin_amdgcn_global_load_lds((gas1)src, (las3)&B[q << 2], 16, 0, 0);
    }
  };
  auto dswriteA = [&](int buf) {
    float* A = AsB + buf * (32 * 64);
    #pragma unroll
    for (int i = 0; i < 2; ++i) {
      int q = tid + (i << 8);
      int r = q >> 4, c0 = (q & 15) << 2;
      *(float4*)&A[(r << 6) + (c0 ^ ((r & 1) << 4))] = areg[i];
    }
  };
  auto compute = [&](int buf) {
    const float* A = AsB + buf * (32 * 64);
    const float* B = BsB + buf * (32 * 128);
    #pragma unroll
    for (int k4 = 0; k4 < BKC; k4 += 4) {
      int krow = k4 + lg;
      int sw = (krow & 1) << 4;
      double a0 = (double)A[(krow << 6) + (((wr << 5) + lr) ^ sw)];
      double a1 = (double)A[(krow << 6) + (((wr << 5) + 16 + lr) ^ sw)];
      double b0 = (double)B[(krow << 7) + (((wc << 6) + lr) ^ sw)];
      double b1 = (double)B[(krow << 7) + (((wc << 6) + 16 + lr) ^ sw)];
      double b2 = (double)B[(krow << 7) + (((wc << 6) + 32 + lr) ^ sw)];
      double b3 = (double)B[(krow << 7) + (((wc << 6) + 48 + lr) ^ sw)];
      acc[0][0] = __builtin_amdgcn_mfma_f64_16x16x4f64(a0, b0, acc[0][0], 0, 0, 0);
      acc[0][1] = __builtin_amdgcn_mfma_f64_16x16x4f64(a0, b1, acc[0][1], 0, 0, 0);
      acc[0][2] = __builtin_amdgcn_mfma_f64_16x16x4f64(a0, b2, acc[0][2], 0, 0, 0);
      acc[0][3] = __builtin_amdgcn_mfma_f64_16x16x4f64(a0, b3, acc[0][3], 0, 0, 0);
      acc[1][0] = __builtin_amdgcn_mfma_f64_16x16x4f64(a1, b0, acc[1][0], 0, 0, 0);
      acc[1][1] = __builtin_amdgcn_mfma_f64_16x16x4f64(a1, b1, acc[1][1], 0, 0, 0);
      acc[1][2] = __builtin_amdgcn_mfma_f64_16x16x4f64(a1, b2, acc[1][2], 0, 0, 0);
      acc[1][3] = __builtin_amdgcn_mfma_f64_16x16x4f64(a1, b3, acc[1][3], 0, 0, 0);
    }
  };

  // prologue + single-barrier double-buffered K loop
  gloadA(0);
  gloadB_lds(0, 0);
  dswriteA(0);
  for (int c = 0; c < NCHUNK; ++c) {
    __syncthreads();                 // buf[c&1] ready; buf[(c+1)&1] free
    if (c + 1 < NCHUNK) {
      gloadB_lds(c + 1, (c + 1) & 1);  // async DMA overlaps compute
      gloadA(c + 1);
    }
    compute(c & 1);
    if (c + 1 < NCHUNK) dswriteA((c + 1) & 1);
  }

  // --- probe the D fragment layout (post-loop: no reg pressure in K-loop) ---
  int rmap[4], cmap[4];
  {
    d4 z = (d4)0.0;
    double apr = (lg == 0) ? (double)lr : 0.0;
    double bpr = (lg == 0) ? 1.0 : 0.0;
    d4 dr = __builtin_amdgcn_mfma_f64_16x16x4f64(apr, bpr, z, 0, 0, 0);
    double apc = (lg == 0) ? 1.0 : 0.0;
    double bpc = (lg == 0) ? (double)lr : 0.0;
    d4 dc = __builtin_amdgcn_mfma_f64_16x16x4f64(apc, bpc, z, 0, 0, 0);
    #pragma unroll
    for (int r = 0; r < 4; ++r) { rmap[r] = (int)dr[r]; cmap[r] = (int)dc[r]; }
  }

  // -------- epilogue: bias+relu -> xs (fp64), fused head dots, atomics ------
  double* xs = (double*)smraw;                 // [64][65] doubles = 33280 B
  float* hwS = (float*)(smraw + 64 * 65 * 8);  // [54][64] floats  = 13824 B
  double sacc[14];
  #pragma unroll
  for (int it = 0; it < 14; ++it) sacc[it] = 0.0;

  #pragma unroll
  for (int hh = 0; hh < 2; ++hh) {
    __syncthreads();
    for (int e = tid; e < 54 * 64; e += 256) {
      int o = e >> 6, j = e & 63;
      int oc = oc0 + (hh << 6) + j;
      hwS[e] = (o < 18) ? cls_w[(o << 9) + oc] : reg_w[((o - 18) << 9) + oc];
    }
    if (wc == hh) {
      #pragma unroll
      for (int t = 0; t < 2; ++t) {
        #pragma unroll
        for (int u = 0; u < 4; ++u) {
          #pragma unroll
          for (int r = 0; r < 4; ++r) {
            int ocl = (u << 4) + cmap[r];
            int pxl = (wr << 5) + (t << 4) + rmap[r];
            double v = acc[t][u][r] + (double)conv_b[oc0 + (hh << 6) + ocl];
            xs[pxl * 65 + ocl] = (v > 0.0) ? v : 0.0;
          }
        }
      }
    }
    __syncthreads();
    #pragma unroll
    for (int it = 0; it < 14; ++it) {
      int e = tid + (it << 8);
      if (e < 54 * 64) {
        int o = e >> 6, px = e & 63;
        const double* xr = &xs[px * 65];
        const float* hr = &hwS[o << 6];
        double s = 0.0;
        #pragma unroll
        for (int j = 0; j < 64; ++j) s += xr[j] * (double)hr[j];
        sacc[it] += s;
      }
    }
  }
  int pixbase = (h << 7) + w0;
  #pragma unroll
  for (int it = 0; it < 14; ++it) {
    int e = tid + (it << 8);
    if (e < 54 * 64) {
      int o = e >> 6, px = e & 63;
      atomicAdd(&predacc[(size_t)(pixbase + px) * 54 + o], sacc[it]);
    }
  }
}

// --------- verification: recompute x for 4 probe pixels (ic-split) ----------
__global__ __launch_bounds__(256) void chk_x_k(
    const float* __restrict__ feat, const float* __restrict__ c3w,
    double* __restrict__ xraw)
{
  int task = blockIdx.x * 256 + threadIdx.x;  // 16384 = 4px * 512oc * 8icg
  int pi = task >> 12;
  int oc = (task >> 3) & 511;
  int icg = task & 7;
  const int pixs[4] = {0, 5437, 10240, 16383};
  int pix = pixs[pi];
  int h = pix >> 7, w = pix & 127;
  double s = 0.0;
  for (int ic = icg * 64; ic < icg * 64 + 64; ++ic) {
    const float* f = &feat[ic << 14];
    const float* wp = &c3w[(size_t)(oc * 512 + ic) * 9];
    #pragma unroll
    for (int kh = -1; kh <= 1; ++kh) {
      int hp = h + kh;
      if ((unsigned)hp >= 128u) continue;
      #pragma unroll
      for (int kw = -1; kw <= 1; ++kw) {
        int wq = w + kw;
        if ((unsigned)wq >= 128u) continue;
        s += (double)f[(hp << 7) + wq] * (double)wp[(kh + 1) * 3 + (kw + 1)];
      }
    }
  }
  atomicAdd(&xraw[(pi << 9) + oc], s);
}

__global__ __launch_bounds__(256) void chk_cmp_k(
    const double* __restrict__ xraw, const float* __restrict__ c3b,
    const float* __restrict__ cls_w, const float* __restrict__ reg_w,
    const double* __restrict__ predacc, double* flagd)
{
  int t = threadIdx.x;
  if (t >= 216) return;
  int pi = t / 54, o = t - pi * 54;
  const int pixs[4] = {0, 5437, 10240, 16383};
  const float* wrow = (o < 18) ? &cls_w[o << 9] : &reg_w[(o - 18) << 9];
  const double* xr = &xraw[pi << 9];
  double s = 0.0;
  for (int j = 0; j < 512; ++j) {
    double x = xr[j] + (double)c3b[j];
    x = x > 0.0 ? x : 0.0;
    s += x * (double)wrow[j];
  }
  double got = predacc[(size_t)pixs[pi] * 54 + o];
  if (fabs(got - s) > 1e-6) *flagd = 1.0;
}

__global__ __launch_bounds__(256) void rezero_k(const double* __restrict__ flagd,
                                                double* p, int n) {
  if (*flagd == 0.0) return;
  int i = blockIdx.x * 256 + threadIdx.x;
  if (i < n) p[i] = 0.0;
}

// R1-proven VALU conv+heads fallback, gated on flag
__global__ __launch_bounds__(256) void conv_fb_k(
    const double* __restrict__ flagd,
    const float* __restrict__ feat, const float* __restrict__ wt,
    const float* __restrict__ conv_b, const float* __restrict__ cls_w,
    const float* __restrict__ reg_w, double* __restrict__ predacc)
{
  if (*flagd == 0.0) return;
  __shared__ __align__(16) char smraw[47104];
  double* As = (double*)smraw;
  double* Bs = As + 2048;
  int tid = threadIdx.x;
  int bid = blockIdx.x;
  int pt = bid & 255, ot = bid >> 8;
  int h = pt >> 1, w0 = (pt & 1) << 6;
  int oc0 = ot << 6;
  int tx = tid & 15, ty = tid >> 4;

  double acc[4][4];
  #pragma unroll
  for (int i = 0; i < 4; ++i)
    #pragma unroll
    for (int j = 0; j < 4; ++j) acc[i][j] = 0.0;

  for (int tap = 0; tap < 9; ++tap) {
    int kh = tap / 3 - 1, kw = tap % 3 - 1;
    int hp = h + kh;
    bool okh = (hp >= 0) && (hp < HF);
    for (int icc = 0; icc < 16; ++icc) {
      int ic0 = icc << 5;
      __syncthreads();
      #pragma unroll
      for (int i = 0; i < 8; ++i) {
        int e = tid + (i << 8);
        int icl = e >> 6;
        int lx = e & 63;
        int wp = w0 + lx + kw;
        float v = 0.0f;
        if (okh && wp >= 0 && wp < WF)
          v = feat[((ic0 + icl) << 14) + (hp << 7) + wp];
        As[(icl << 6) + lx] = (double)v;
        Bs[(icl << 6) + lx] =
            (double)wt[((((tap << 9) + ic0 + icl)) << 9) + oc0 + lx];
      }
      __syncthreads();
      #pragma unroll
      for (int k = 0; k < 32; ++k) {
        const double* ar = &As[(k << 6) + (ty << 2)];
        const double* br = &Bs[(k << 6) + (tx << 2)];
        double a0 = ar[0], a1 = ar[1], a2 = ar[2], a3 = ar[3];
        double b0 = br[0], b1 = br[1], b2 = br[2], b3 = br[3];
        acc[0][0] += a0 * b0; acc[0][1] += a0 * b1; acc[0][2] += a0 * b2; acc[0][3] += a0 * b3;
        acc[1][0] += a1 * b0; acc[1][1] += a1 * b1; acc[1][2] += a1 * b2; acc[1][3] += a1 * b3;
        acc[2][0] += a2 * b0; acc[2][1] += a2 * b1; acc[2][2] += a2 * b2; acc[2][3] += a2 * b3;
        acc[3][0] += a3 * b0; acc[3][1] += a3 * b1; acc[3][2] += a3 * b2; acc[3][3] += a3 * b3;
      }
    }
  }
  __syncthreads();
  double* xs = (double*)smraw;
  float* hwS = (float*)(smraw + 64 * 65 * 8);
  #pragma unroll
  for (int i = 0; i < 4; ++i) {
    int px = (ty << 2) + i;
    #pragma unroll
    for (int j = 0; j < 4; ++j) {
      int oc = (tx << 2) + j;
      double v = acc[i][j] + (double)conv_b[oc0 + oc];
      xs[px * 65 + oc] = v > 0.0 ? v : 0.0;
    }
  }
  for (int e = tid; e < 54 * 64; e += 256) {
    int o = e >> 6, ocl = e & 63;
    hwS[e] = (o < 18) ? cls_w[(o << 9) + oc0 + ocl]
                      : reg_w[((o - 18) << 9) + oc0 + ocl];
  }
  __syncthreads();
  int pixbase = (h << 7) + w0;
  for (int e = tid; e < 54 * 64; e += 256) {
    int px = e & 63, o = e >> 6;
    const double* xr = &xs[px * 65];
    const float* hr = &hwS[o << 6];
    double s = 0.0;
    #pragma unroll
    for (int j = 0; j < 64; ++j) s += xr[j] * (double)hr[j];
    atomicAdd(&predacc[(pixbase + px) * 54 + o], s);
  }
}

// per-anchor: heads bias, outputs, anchors, make_roi, score, sort entry
__global__ __launch_bounds__(256) void anchor_k(
    const double* __restrict__ predacc, const float* __restrict__ cls_b,
    const float* __restrict__ reg_b, float* __restrict__ out,
    double* __restrict__ roi_all, double* __restrict__ scores_d,
    ulonglong2* __restrict__ sortb)
{
  #pragma clang fp contract(off)
  int a = blockIdx.x * 256 + threadIdx.x;
  if (a >= NSORT) return;
  if (a >= NANC) {
    sortb[a] = make_ulonglong2(0xFFF0000000000000ULL, 0xFFFFFFFFULL);
    return;
  }
  int pix = a / 9;
  int k = a - pix * 9;
  int h = pix >> 7, wq = pix & 127;
  const double* pa = &predacc[pix * 54];
  double c0 = pa[2 * k] + (double)cls_b[2 * k];
  double c1 = pa[2 * k + 1] + (double)cls_b[2 * k + 1];
  double d0 = pa[18 + 4 * k + 0] + (double)reg_b[4 * k + 0];
  double d1 = pa[18 + 4 * k + 1] + (double)reg_b[4 * k + 1];
  double d2 = pa[18 + 4 * k + 2] + (double)reg_b[4 * k + 2];
  double d3 = pa[18 + 4 * k + 3] + (double)reg_b[4 * k + 3];
  out[OFF_CLS + a * 2 + 0] = (float)c0;
  out[OFF_CLS + a * 2 + 1] = (float)c1;
  out[OFF_REG + a * 4 + 0] = (float)d0;
  out[OFF_REG + a * 4 + 1] = (float)d1;
  out[OFF_REG + a * 4 + 2] = (float)d2;
  out[OFF_REG + a * 4 + 3] = (float)d3;
  int ir = k / 3, is = k - ir * 3;
  double ratio = (ir == 0) ? 0.5 : (ir == 1 ? 1.0 : 2.0);
  double asz = (is == 0) ? 8.0 : (is == 1 ? 16.0 : 32.0);
  double sq = sqrt(ratio);
  double wa = (16.0 * asz) / sq;
  double ha = (16.0 * asz) * sq;
  double cx = (h + 0.5) * 16.0;
  double cy = (wq + 0.5) * 16.0;
  double A0 = (double)(float)rint(cx - wa * 0.5);
  double A1 = (double)(float)rint(cy - ha * 0.5);
  double A2 = (double)(float)rint(cx + wa * 0.5);
  double A3 = (double)(float)rint(cy + ha * 0.5);
  double aw = A2 - A0, ah = A3 - A1;
  double acx = A0 + aw * 0.5, acy = A1 + ah * 0.5;
  double ccx = d0 * aw + acx;
  double ccy = d1 * ah + acy;
  double wr = exp(d2) * aw;
  double hh = exp(d3) * ah;
  double r0 = ccx - wr * 0.5;
  double r1 = ccy - hh * 0.5;
  double r2 = ccx + wr * 0.5;
  double r3 = ccy + hh * 0.5;
  r0 = fmax(r0, 0.0); r1 = fmax(r1, 0.0); r2 = fmax(r2, 0.0); r3 = fmax(r3, 0.0);
  r3 = (r3 > 2048.0) ? 2047.0 : r3;
  r2 = (r2 > 2048.0) ? 2047.0 : r2;
  bool valid = ((r2 - r0) > 16.0) && ((r3 - r1) > 16.0);
  double score = valid ? c1 : -__builtin_huge_val();
  roi_all[a * 4 + 0] = r0;
  roi_all[a * 4 + 1] = r1;
  roi_all[a * 4 + 2] = r2;
  roi_all[a * 4 + 3] = r3;
  scores_d[a] = score;
  u64 u = (u64)__double_as_longlong(score);
  u64 m = (u >> 63) ? ~u : (u | 0x8000000000000000ULL);
  sortb[a] = make_ulonglong2(~m, (u64)a);
}

// ------------------------- radix-select top-6000 ----------------------------
__global__ __launch_bounds__(1024) void init_sel_k(unsigned* hist, u64* selp,
                                                   unsigned* cnt) {
  int t = blockIdx.x * 1024 + threadIdx.x;
  if (t < 2048) hist[t] = 0;
  if (t == 0) { selp[0] = 0; selp[1] = 0; cnt[0] = 0; cnt[1] = 0; }
}

__global__ __launch_bounds__(1024) void hist_k(const ulonglong2* __restrict__ sortb,
                                               unsigned* __restrict__ hist,
                                               const u64* __restrict__ selp,
                                               int pass) {
  __shared__ unsigned h[2048];
  int t = threadIdx.x;
  h[t] = 0; h[t + 1024] = 0;
  __syncthreads();
  const int SH[3] = {53, 42, 31};
  const u64 PM[3] = {0ULL, 0xFFE0000000000000ULL, 0xFFFFFC0000000000ULL};
  u64 pfx = selp[0];
  u64 pm = PM[pass];
  int sh = SH[pass];
  for (int e = blockIdx.x * 1024 + t; e < NSORT; e += gridDim.x * 1024) {
    u64 k = sortb[e].x;
    if ((k & pm) == pfx)
      atomicAdd(&h[(unsigned)((k >> sh) & 2047)], 1u);
  }
  __syncthreads();
  if (h[t]) atomicAdd(&hist[t], h[t]);
  if (h[t + 1024]) atomicAdd(&hist[t + 1024], h[t + 1024]);
}

__global__ __launch_bounds__(1024) void scan_k(unsigned* hist, u64* selp, int pass) {
  __shared__ unsigned h[2048];
  int t = threadIdx.x;
  h[t] = hist[t]; h[t + 1024] = hist[t + 1024];
  hist[t] = 0; hist[t + 1024] = 0;
  __syncthreads();
  if (t == 0) {
    const int SH[3] = {53, 42, 31};
    u64 cum = selp[1];
    u64 pfx = selp[0];
    int b = 0;
    for (; b < 2047; ++b) {
      if (cum + h[b] >= (u64)TOPN) break;
      cum += h[b];
    }
    selp[0] = pfx | ((u64)b << SH[pass]);
    selp[1] = cum;
  }
}

__global__ __launch_bounds__(1024) void compact_k(
    const ulonglong2* __restrict__ sortb, const u64* __restrict__ selp,
    ulonglong2* __restrict__ cand, ulonglong2* __restrict__ bcand,
    unsigned* __restrict__ cnt) {
  u64 pfx = selp[0];
  const u64 M33 = 0xFFFFFFFF80000000ULL;
  for (int e = blockIdx.x * 1024 + threadIdx.x; e < NSORT; e += gridDim.x * 1024) {
    ulonglong2 v = sortb[e];
    u64 top = v.x & M33;
    if (top < pfx) {
      unsigned p = atomicAdd(&cnt[0], 1u);
      if (p < NCAND) cand[p] = v;
    } else if (top == pfx) {
      unsigned p = atomicAdd(&cnt[1], 1u);
      if (p < NBCAP) bcand[p] = v;
    }
  }
}

__global__ __launch_bounds__(1024) void fill_k(ulonglong2* cand,
                                               const ulonglong2* __restrict__ bcand,
                                               const unsigned* __restrict__ cnt) {
  int t = blockIdx.x * 1024 + threadIdx.x;
  unsigned ci = cnt[0];
  unsigned cb = cnt[1] < NBCAP ? cnt[1] : NBCAP;
  if (t >= (int)ci) {
    if (t < (int)(ci + cb)) cand[t] = bcand[t - ci];
    else if (t < NCAND) cand[t] = make_ulonglong2(~0ULL, ~0ULL);
  }
}

// ------------------- single-block LDS bitonic sort of 8192 ------------------
__device__ __forceinline__ bool sless(ulonglong2 A, ulonglong2 B) {
  return (A.x < B.x) || (A.x == B.x && A.y < B.y);
}

__global__ __launch_bounds__(1024) void sort8k_k(ulonglong2* d) {
  extern __shared__ ulonglong2 s[];   // 8192 * 16B = 128 KB dynamic LDS
  int t = threadIdx.x;
  #pragma unroll
  for (int i = 0; i < 8; ++i) s[t + (i << 10)] = d[t + (i << 10)];
  __syncthreads();
  for (int k = 2; k <= NCAND; k <<= 1) {
    for (int j = k >> 1; j >= 1; j >>= 1) {
      #pragma unroll
      for (int q = 0; q < 4; ++q) {
        int p = t + (q << 10);
        int li = ((p & ~(j - 1)) << 1) | (p & (j - 1));
        int pa = li | j;
        bool asc = ((li & k) == 0);
        ulonglong2 A = s[li], B = s[pa];
        bool sw = asc ? sless(B, A) : sless(A, B);
        if (sw) { s[li] = B; s[pa] = A; }
      }
      __syncthreads();
    }
  }
  #pragma unroll
  for (int i = 0; i < 8; ++i) d[t + (i << 10)] = s[t + (i << 10)];
}

// ----------------------------- NMS pipeline ---------------------------------
__global__ __launch_bounds__(1024) void prep_k(
    const ulonglong2* __restrict__ sorted, const double* __restrict__ roi_all,
    const double* __restrict__ scores_d, double* __restrict__ boxes,
    u64* __restrict__ removed)
{
  int t = threadIdx.x;
  for (int i = t; i < TOPN; i += 1024) {
    unsigned idx = (unsigned)sorted[i].y;
    double b0 = 0, b1 = 0, b2 = 0, b3 = 0;
    if (idx < NANC) {
      b0 = roi_all[idx * 4 + 0];
      b1 = roi_all[idx * 4 + 1];
      b2 = roi_all[idx * 4 + 2];
      b3 = roi_all[idx * 4 + 3];
    }
    boxes[i * 4 + 0] = b0; boxes[i * 4 + 1] = b1;
    boxes[i * 4 + 2] = b2; boxes[i * 4 + 3] = b3;
  }
  if (t < NWORDS) {
    u64 wdd = (t == NWORDS - 1) ? 0xFFFF000000000000ULL : 0ULL;
    for (int b = 0; b < 64; ++b) {
      int i = t * 64 + b;
      if (i >= TOPN) break;
      unsigned idx = (unsigned)sorted[i].y;
      bool dead = true;
      if (idx < NANC) dead = isinf(scores_d[idx]);
      if (dead) wdd |= (1ULL << b);
    }
    removed[t] = wdd;
  }
}

// suppression bitmask (triangular: only words w >= chunk(i) are written/read)
__global__ __launch_bounds__(256) void mask_k(const double* __restrict__ boxes,
                                              u64* __restrict__ mask) {
  #pragma clang fp contract(off)
  int gw = (blockIdx.x * 256 + threadIdx.x) >> 6;
  int lane = threadIdx.x & 63;
  int i = gw / NWORDS, wj = gw - i * NWORDS;
  if (i >= TOPN) return;
  if (wj < (i >> 6)) return;
  double ix1 = boxes[i * 4 + 0], iy1 = boxes[i * 4 + 1];
  double ix2 = boxes[i * 4 + 2], iy2 = boxes[i * 4 + 3];
  double tx1 = trunc(ix1), ty1 = trunc(iy1), tx2 = trunc(ix2), ty2 = trunc(iy2);
  double gminx = fmin(tx1, tx2), gmaxx = fmax(tx1, tx2);
  double gminy = fmin(ty1, ty2), gmaxy = fmax(ty1, ty2);
  double gw_ = trunc(ix2 - ix1), gh_ = trunc(iy2 - iy1);
  int j = wj * 64 + lane;
  bool pred = false;
  if (j < TOPN && j > i) {
    double jx1 = boxes[j * 4 + 0], jy1 = boxes[j * 4 + 1];
    double jx2 = boxes[j * 4 + 2], jy2 = boxes[j * 4 + 3];
    double aw = jx2 - jx1, ah = jy2 - jy1;
    double aminx = fmin(jx1, jx2), amaxx = fmax(jx1, jx2);
    double aminy = fmin(jy1, jy2), amaxy = fmax(jy1, jy2);
    double iw = fmin(aminx, gminx) + aw + gw_ - fmax(amaxx, gmaxx);
    iw = fmax(iw, 0.0);
    double ih = fmin(aminy, gminy) + ah + gh_ - fmax(amaxy, gmaxy);
    ih = fmax(ih, 0.0);
    double inter = iw * ih;
    double uni = aw * ah + gw_ * gh_ - inter;
    pred = (inter / uni >= 0.7);
  }
  u64 bal = __ballot(pred);
  if (lane == 0) mask[(size_t)i * NWORDS + wj] = bal;
}

// chunked greedy suppression
__global__ __launch_bounds__(1024) void nms_chunk_k(const u64* __restrict__ mask,
                                                    u64* removed_g) {
  __shared__ u64 rem[NWORDS];
  __shared__ u64 aliveSh;
  int t = threadIdx.x;
  int lane = t & 63;
  int wvid = t >> 6;
  if (t < NWORDS) rem[t] = removed_g[t];
  __syncthreads();
  for (int c = 0; c < NWORDS; ++c) {
    if (wvid == 0) {
      int i = c * 64 + lane;
      u64 diag = (i < TOPN) ? mask[(size_t)i * NWORDS + c] : 0ULL;
      u64 local = rem[c];
      #pragma unroll 1
      for (int j = 0; j < 64; ++j) {
        u64 dj = __shfl(diag, j);
        if (!((local >> j) & 1ULL)) local |= dj;
      }
      if (lane == 0) { rem[c] = local; aliveSh = ~local; }
    }
    __syncthreads();
    u64 alive = aliveSh;
    int nw = NWORDS - 1 - c;
    if (nw > 0 && alive) {
      int npairs = 64 * nw;
      for (int p = t; p < npairs; p += 1024) {
        int j = p / nw;
        int w = c + 1 + (p - j * nw);
        if ((alive >> j) & 1ULL) {
          int i = c * 64 + j;
          if (i < TOPN) {
            u64 v = mask[(size_t)i * NWORDS + w];
            if (v) atomicOr(&rem[w], v);
          }
        }
      }
    }
    __syncthreads();
  }
  if (t < NWORDS) removed_g[t] = rem[t];
}

__global__ __launch_bounds__(256) void out_k(const u64* __restrict__ removed,
                                             const double* __restrict__ boxes,
                                             float* __restrict__ out) {
  __shared__ int pref[NWORDS + 1];
  __shared__ u64 keepw[NWORDS];
  int t = threadIdx.x;
  for (int i = t; i < NOUT * 4; i += 256) out[i] = 0.0f;
  if (t < NWORDS) keepw[t] = ~removed[t];
  __syncthreads();
  if (t == 0) {
    int s = 0;
    for (int w = 0; w < NWORDS; ++w) { pref[w] = s; s += __popcll(keepw[w]); }
    pref[NWORDS] = s;
  }
  __syncthreads();
  for (int i = t; i < TOPN; i += 256) {
    u64 kw = keepw[i >> 6];
    if ((kw >> (i & 63)) & 1ULL) {
      int rank = pref[i >> 6] + __popcll(kw & ((1ULL << (i & 63)) - 1ULL));
      if (rank < NOUT) {
        out[rank * 4 + 0] = (float)boxes[i * 4 + 0];
        out[rank * 4 + 1] = (float)boxes[i * 4 + 1];
        out[rank * 4 + 2] = (float)boxes[i * 4 + 2];
        out[rank * 4 + 3] = (float)boxes[i * 4 + 3];
      }
    }
  }
}

extern "C" void kernel_launch(void* const* d_in, const int* in_sizes, int n_in,
                              void* d_out, int out_size, void* d_ws, size_t ws_size,
                              hipStream_t stream) {
  const float* feat = (const float*)d_in[0];
  const float* c3w = (const float*)d_in[1];
  const float* c3b = (const float*)d_in[2];
  const float* clw = (const float*)d_in[3];
  const float* clb = (const float*)d_in[4];
  const float* rgw = (const float*)d_in[5];
  const float* rgb = (const float*)d_in[6];
  float* out = (float*)d_out;
  char* ws = (char*)d_ws;
  size_t off = 0;
  auto alloc = [&](size_t bytes) {
    size_t o = off;
    off = (off + bytes + 255) & ~(size_t)255;
    return o;
  };
  double* predacc = (double*)(ws + alloc(16384ULL * 54 * 8));     // 7.08 MB
  double* flagd = (double*)(ws + alloc(256));
  float* wt = (float*)(ws + alloc(2359296ULL * 4));               // 9.44 MB
  double* roi_all = (double*)(ws + alloc((size_t)NANC * 4 * 8));  // 4.72 MB
  double* scores_d = (double*)(ws + alloc((size_t)NANC * 8));     // 1.18 MB
  ulonglong2* sortb = (ulonglong2*)(ws + alloc((size_t)NSORT * 16)); // 4.19 MB
  double* boxes = (double*)(ws + alloc((size_t)TOPN * 4 * 8));    // 0.19 MB
  u64* mask = (u64*)(ws + alloc((size_t)TOPN * NWORDS * 8));      // 4.51 MB
  u64* removed = (u64*)(ws + alloc(NWORDS * 8));
  double* xraw = (double*)(ws + alloc(4 * 512 * 8));              // 16 KB
  unsigned* hist = (unsigned*)(ws + alloc(2048 * 4));             // 8 KB
  u64* selp = (u64*)(ws + alloc(256));
  unsigned* cntb = (unsigned*)(ws + alloc(256));
  ulonglong2* cand = (ulonglong2*)(ws + alloc((size_t)NCAND * 16));   // 128 KB
  ulonglong2* bcand = (ulonglong2*)(ws + alloc((size_t)NBCAP * 16));  // 32 KB
  (void)ws_size; (void)out_size; (void)in_sizes; (void)n_in;

  const int NPRED = 16384 * 54;
  hipLaunchKernelGGL(zero2_k, dim3((NPRED + 32 + 2048 + 255) / 256), dim3(256), 0,
                     stream, predacc, NPRED + 32, xraw, 2048);
  hipLaunchKernelGGL(wtrans_k, dim3(512), dim3(256), 0, stream, c3w, wt);
  hipLaunchKernelGGL(conv_mfma_k, dim3(1024), dim3(256), 0, stream,
                     feat, wt, c3b, clw, rgw, predacc);
  // verify MFMA result at 4 probe pixels; gated VALU fallback
  hipLaunchKernelGGL(chk_x_k, dim3(64), dim3(256), 0, stream, feat, c3w, xraw);
  hipLaunchKernelGGL(chk_cmp_k, dim3(1), dim3(256), 0, stream,
                     xraw, c3b, clw, rgw, predacc, flagd);
  hipLaunchKernelGGL(rezero_k, dim3((NPRED + 255) / 256), dim3(256), 0, stream,
                     flagd, predacc, NPRED);
  hipLaunchKernelGGL(conv_fb_k, dim3(2048), dim3(256), 0, stream,
                     flagd, feat, wt, c3b, clw, rgw, predacc);
  hipLaunchKernelGGL(anchor_k, dim3(NSORT / 256), dim3(256), 0, stream,
                     predacc, clb, rgb, out, roi_all, scores_d, sortb);
  // radix-select top-6000
  hipLaunchKernelGGL(init_sel_k, dim3(2), dim3(1024), 0, stream, hist, selp, cntb);
  for (int pass = 0; pass < 3; ++pass) {
    hipLaunchKernelGGL(hist_k, dim3(128), dim3(1024), 0, stream,
                       sortb, hist, selp, pass);
    hipLaunchKernelGGL(scan_k, dim3(1), dim3(1024), 0, stream, hist, selp, pass);
  }
  hipLaunchKernelGGL(compact_k, dim3(128), dim3(1024), 0, stream,
                     sortb, selp, cand, bcand, cntb);
  hipLaunchKernelGGL(fill_k, dim3(NCAND / 1024), dim3(1024), 0, stream,
                     cand, bcand, cntb);
  hipLaunchKernelGGL(sort8k_k, dim3(1), dim3(1024), NCAND * 16, stream, cand);
  // NMS
  hipLaunchKernelGGL(prep_k, dim3(1), dim3(1024), 0, stream,
                     cand, roi_all, scores_d, boxes, removed);
  hipLaunchKernelGGL(mask_k, dim3(TOPN * NWORDS / 4), dim3(256), 0, stream,
                     boxes, mask);
  hipLaunchKernelGGL(nms_chunk_k, dim3(1), dim3(1024), 0, stream, mask, removed);
  hipLaunchKernelGGL(out_k, dim3(1), dim3(256), 0, stream, removed, boxes, out);
}

// Round 9
// 2378.868 us; speedup vs baseline: 1.2141x; 1.0590x over previous
//
#include <hip/hip_runtime.h>

#define HF 128
#define WF 128
#define KANC 9
#define NANC (HF*WF*KANC)      // 147456
#define NSORT 262144
#define TOPN 6000
#define NWORDS 94              // ceil(6000/64)
#define NOUT 2000
#define OFF_CLS 8000
#define OFF_REG 302912
#define NCAND 8192
#define NBCAP 2048

typedef unsigned long long u64;
typedef double d4 __attribute__((ext_vector_type(4)));
typedef const __attribute__((address_space(1))) void* gas1;
typedef __attribute__((address_space(3))) void* las3;

__global__ __launch_bounds__(256) void zero3_k(double* p1, int n1,
                                               double* p2, int n2,
                                               unsigned* hist, u64* selp,
                                               unsigned* cnt) {
  int i = blockIdx.x * 256 + threadIdx.x;
  if (i < n1) p1[i] = 0.0;
  else if (i - n1 < n2) p2[i - n1] = 0.0;
  if (i < 2048) hist[i] = 0;
  if (i == 0) { selp[0] = 0; selp[1] = 0; cnt[0] = 0; cnt[1] = 0; }
}

// conv3_w [oc][ic][kh][kw] -> wt [tap][ic][oc], LDS-tiled transpose.
__global__ __launch_bounds__(256) void wtrans_k(const float* __restrict__ w,
                                                float* __restrict__ wt) {
  __shared__ float ld[64 * 73];
  int t = threadIdx.x;
  int ocg = blockIdx.x & 7, icg = blockIdx.x >> 3;
  int oc0 = ocg << 6, ic0 = icg << 3;
  #pragma unroll
  for (int rep = 0; rep < 18; ++rep) {
    int idx = rep * 256 + t;            // 0..4607
    int row = idx / 72, col = idx - row * 72;
    ld[row * 73 + col] = w[(size_t)(oc0 + row) * 4608 + ic0 * 9 + col];
  }
  __syncthreads();
  #pragma unroll
  for (int rep = 0; rep < 18; ++rep) {
    int idx = rep * 256 + t;
    int pair = idx >> 6, oc = idx & 63;
    int tap = pair % 9, ic = pair / 9;
    wt[(size_t)tap * 262144 + (size_t)(ic0 + ic) * 512 + oc0 + oc] =
        ld[oc * 73 + ic * 9 + tap];
  }
}

// ---------------------------------------------------------------------------
// conv3x3(512->512) as fp64-MFMA GEMM, heads fused in epilogue.
// 64px x 64oc tile, 32KB LDS -> 4 blocks/CU; grid 2048 = 2 exact phases.
// 4 waves (2x2), each 32x32; B via global_load_lds (pre-swizzled source);
// A reg-staged. D-fragment layout probed post-loop (verified R4-R8).
// ---------------------------------------------------------------------------
#define BKC 32
#define NCHUNK 144

__global__ __launch_bounds__(256, 4) void conv_mfma_k(
    const float* __restrict__ feat, const float* __restrict__ wt,
    const float* __restrict__ conv_b, const float* __restrict__ cls_w,
    const float* __restrict__ reg_w, double* __restrict__ predacc)
{
  __shared__ __align__(16) char smraw[32768];
  float* AsB = (float*)smraw;                     // [2][32*64]
  float* BsB = (float*)(smraw + 2 * 2048 * 4);    // [2][32*64]
  int tid = threadIdx.x;
  int bid = blockIdx.x;
  int pt = bid & 255, ot = bid >> 8;              // ot 0..7
  int h = pt >> 1, w0 = (pt & 1) << 6;
  int oc0 = ot << 6;
  int wv = tid >> 6, l = tid & 63;
  int wr = wv >> 1, wc = wv & 1;                  // 2x2 waves of 32px x 32oc
  int lg = l >> 4, lr = l & 15;

  d4 acc[2][2];
  #pragma unroll
  for (int t = 0; t < 2; ++t)
    #pragma unroll
    for (int u = 0; u < 2; ++u) acc[t][u] = (d4)0.0;

  float4 areg[2];

  auto gloadA = [&](int c) {
    int tap = c >> 4, ic0 = (c & 15) << 5;
    int kh = tap / 3 - 1, kw = tap % 3 - 1;
    int hp = h + kh;
    bool okh = ((unsigned)hp < 128u);
    #pragma unroll
    for (int i = 0; i < 2; ++i) {
      int q = tid + (i << 8);
      int r = q >> 4, c0 = (q & 15) << 2;
      float v0 = 0.f, v1 = 0.f, v2 = 0.f, v3 = 0.f;
      const float* src = &feat[((ic0 + r) << 14) + (hp << 7)];
      int wp = w0 + c0 + kw;
      if (okh) {
        if ((unsigned)(wp + 0) < 128u) v0 = src[wp + 0];
        if ((unsigned)(wp + 1) < 128u) v1 = src[wp + 1];
        if ((unsigned)(wp + 2) < 128u) v2 = src[wp + 2];
        if ((unsigned)(wp + 3) < 128u) v3 = src[wp + 3];
      }
      areg[i] = make_float4(v0, v1, v2, v3);
    }
  };
  // B: global->LDS DMA, linear dest (q*16B), swizzle applied to global col.
  auto gloadB_lds = [&](int c, int buf) {
    float* B = BsB + buf * 2048;
    #pragma unroll
    for (int i = 0; i < 2; ++i) {
      int q = tid + (i << 8);
      int r = q >> 4, c0 = (q & 15) << 2;
      const float* src =
          &wt[(size_t)((c << 5) + r) * 512 + oc0 + (c0 ^ ((r & 1) << 4))];
      __builtin_amdgcn_global_load_lds((gas1)src, (las3)&B[q << 2], 16, 0, 0);
    }
  };
  auto dswriteA = [&](int buf) {
    float* A = AsB + buf * 2048;
    #pragma unroll
    for (int i = 0; i < 2; ++i) {
      int q = tid + (i << 8);
      int r = q >> 4, c0 = (q & 15) << 2;
      *(float4*)&A[(r << 6) + (c0 ^ ((r & 1) << 4))] = areg[i];
    }
  };
  auto compute = [&](int buf) {
    const float* A = AsB + buf * 2048;
    const float* B = BsB + buf * 2048;
    #pragma unroll
    for (int k4 = 0; k4 < BKC; k4 += 4) {
      int krow = k4 + lg;
      int sw = (krow & 1) << 4;
      double a0 = (double)A[(krow << 6) + (((wr << 5) + lr) ^ sw)];
      double a1 = (double)A[(krow << 6) + (((wr << 5) + 16 + lr) ^ sw)];
      double b0 = (double)B[(krow << 6) + (((wc << 5) + lr) ^ sw)];
      double b1 = (double)B[(krow << 6) + (((wc << 5) + 16 + lr) ^ sw)];
      acc[0][0] = __builtin_amdgcn_mfma_f64_16x16x4f64(a0, b0, acc[0][0], 0, 0, 0);
      acc[0][1] = __builtin_amdgcn_mfma_f64_16x16x4f64(a0, b1, acc[0][1], 0, 0, 0);
      acc[1][0] = __builtin_amdgcn_mfma_f64_16x16x4f64(a1, b0, acc[1][0], 0, 0, 0);
      acc[1][1] = __builtin_amdgcn_mfma_f64_16x16x4f64(a1, b1, acc[1][1], 0, 0, 0);
    }
  };

  // prologue + single-barrier double-buffered K loop
  gloadA(0);
  gloadB_lds(0, 0);
  dswriteA(0);
  for (int c = 0; c < NCHUNK; ++c) {
    __syncthreads();                 // buf[c&1] ready; buf[(c+1)&1] free
    if (c + 1 < NCHUNK) {
      gloadB_lds(c + 1, (c + 1) & 1);  // async DMA overlaps compute
      gloadA(c + 1);
    }
    compute(c & 1);
    if (c + 1 < NCHUNK) dswriteA((c + 1) & 1);
  }

  // --- probe D fragment layout (post-loop) ---
  int rmap[4], cmap[4];
  {
    d4 z = (d4)0.0;
    double apr = (lg == 0) ? (double)lr : 0.0;
    double bpr = (lg == 0) ? 1.0 : 0.0;
    d4 dr = __builtin_amdgcn_mfma_f64_16x16x4f64(apr, bpr, z, 0, 0, 0);
    double apc = (lg == 0) ? 1.0 : 0.0;
    double bpc = (lg == 0) ? (double)lr : 0.0;
    d4 dc = __builtin_amdgcn_mfma_f64_16x16x4f64(apc, bpc, z, 0, 0, 0);
    #pragma unroll
    for (int r = 0; r < 4; ++r) { rmap[r] = (int)dr[r]; cmap[r] = (int)dc[r]; }
  }

  // ---- epilogue: two 32-px halves: bias+relu -> xs, head dots, atomics ----
  double* xs = (double*)smraw;                  // [32][65] doubles = 16640 B
  float* hwS = (float*)(smraw + 32 * 65 * 8);   // [54][64] floats  = 13824 B
  __syncthreads();                              // LDS free after last compute
  for (int e = tid; e < 54 * 64; e += 256) {
    int o = e >> 6, j = e & 63;
    hwS[e] = (o < 18) ? cls_w[(o << 9) + oc0 + j]
                      : reg_w[((o - 18) << 9) + oc0 + j];
  }
  int pixbase = (h << 7) + w0;
  #pragma unroll
  for (int ph = 0; ph < 2; ++ph) {
    if (wr == ph) {
      #pragma unroll
      for (int t = 0; t < 2; ++t) {
        #pragma unroll
        for (int u = 0; u < 2; ++u) {
          #pragma unroll
          for (int r = 0; r < 4; ++r) {
            int ocl = (wc << 5) + (u << 4) + cmap[r];
            int pxl = (t << 4) + rmap[r];            // 0..31 within half
            double v = acc[t][u][r] + (double)conv_b[oc0 + ocl];
            xs[pxl * 65 + ocl] = (v > 0.0) ? v : 0.0;
          }
        }
      }
    }
    __syncthreads();   // xs (and hwS on first pass) ready
    #pragma unroll
    for (int it = 0; it < 7; ++it) {
      int e = tid + (it << 8);
      if (e < 54 * 32) {
        int o = e >> 5, px = e & 31;
        const double* xr = &xs[px * 65];
        const float* hr = &hwS[o << 6];
        double s = 0.0;
        #pragma unroll
        for (int j = 0; j < 64; ++j) s += xr[j] * (double)hr[j];
        atomicAdd(&predacc[(size_t)(pixbase + (ph << 5) + px) * 54 + o], s);
      }
    }
    __syncthreads();   // dots done before next half overwrites xs
  }
}

// --------- verification: recompute x for 4 probe pixels (ic-split) ----------
__global__ __launch_bounds__(256) void chk_x_k(
    const float* __restrict__ feat, const float* __restrict__ c3w,
    double* __restrict__ xraw)
{
  int task = blockIdx.x * 256 + threadIdx.x;  // 65536 = 4px * 512oc * 32icg
  int pi = task >> 14;
  int oc = (task >> 5) & 511;
  int icg = task & 31;
  const int pixs[4] = {0, 5437, 10240, 16383};
  int pix = pixs[pi];
  int h = pix >> 7, w = pix & 127;
  double s = 0.0;
  for (int ic = icg * 16; ic < icg * 16 + 16; ++ic) {
    const float* f = &feat[ic << 14];
    const float* wp = &c3w[(size_t)(oc * 512 + ic) * 9];
    #pragma unroll
    for (int kh = -1; kh <= 1; ++kh) {
      int hp = h + kh;
      if ((unsigned)hp >= 128u) continue;
      #pragma unroll
      for (int kw = -1; kw <= 1; ++kw) {
        int wq = w + kw;
        if ((unsigned)wq >= 128u) continue;
        s += (double)f[(hp << 7) + wq] * (double)wp[(kh + 1) * 3 + (kw + 1)];
      }
    }
  }
  atomicAdd(&xraw[(pi << 9) + oc], s);
}

__global__ __launch_bounds__(256) void chk_cmp_k(
    const double* __restrict__ xraw, const float* __restrict__ c3b,
    const float* __restrict__ cls_w, const float* __restrict__ reg_w,
    const double* __restrict__ predacc, double* flagd)
{
  int t = threadIdx.x;
  if (t >= 216) return;
  int pi = t / 54, o = t - pi * 54;
  const int pixs[4] = {0, 5437, 10240, 16383};
  const float* wrow = (o < 18) ? &cls_w[o << 9] : &reg_w[(o - 18) << 9];
  const double* xr = &xraw[pi << 9];
  double s = 0.0;
  for (int j = 0; j < 512; ++j) {
    double x = xr[j] + (double)c3b[j];
    x = x > 0.0 ? x : 0.0;
    s += x * (double)wrow[j];
  }
  double got = predacc[(size_t)pixs[pi] * 54 + o];
  if (fabs(got - s) > 1e-6) *flagd = 1.0;
}

__global__ __launch_bounds__(256) void rezero_k(const double* __restrict__ flagd,
                                                double* p, int n) {
  if (*flagd == 0.0) return;
  int i = blockIdx.x * 256 + threadIdx.x;
  if (i < n) p[i] = 0.0;
}

// R1-proven VALU conv+heads fallback, gated on flag
__global__ __launch_bounds__(256) void conv_fb_k(
    const double* __restrict__ flagd,
    const float* __restrict__ feat, const float* __restrict__ wt,
    const float* __restrict__ conv_b, const float* __restrict__ cls_w,
    const float* __restrict__ reg_w, double* __restrict__ predacc)
{
  if (*flagd == 0.0) return;
  __shared__ __align__(16) char smraw[47104];
  double* As = (double*)smraw;
  double* Bs = As + 2048;
  int tid = threadIdx.x;
  int bid = blockIdx.x;
  int pt = bid & 255, ot = bid >> 8;
  int h = pt >> 1, w0 = (pt & 1) << 6;
  int oc0 = ot << 6;
  int tx = tid & 15, ty = tid >> 4;

  double acc[4][4];
  #pragma unroll
  for (int i = 0; i < 4; ++i)
    #pragma unroll
    for (int j = 0; j < 4; ++j) acc[i][j] = 0.0;

  for (int tap = 0; tap < 9; ++tap) {
    int kh = tap / 3 - 1, kw = tap % 3 - 1;
    int hp = h + kh;
    bool okh = (hp >= 0) && (hp < HF);
    for (int icc = 0; icc < 16; ++icc) {
      int ic0 = icc << 5;
      __syncthreads();
      #pragma unroll
      for (int i = 0; i < 8; ++i) {
        int e = tid + (i << 8);
        int icl = e >> 6;
        int lx = e & 63;
        int wp = w0 + lx + kw;
        float v = 0.0f;
        if (okh && wp >= 0 && wp < WF)
          v = feat[((ic0 + icl) << 14) + (hp << 7) + wp];
        As[(icl << 6) + lx] = (double)v;
        Bs[(icl << 6) + lx] =
            (double)wt[((((tap << 9) + ic0 + icl)) << 9) + oc0 + lx];
      }
      __syncthreads();
      #pragma unroll
      for (int k = 0; k < 32; ++k) {
        const double* ar = &As[(k << 6) + (ty << 2)];
        const double* br = &Bs[(k << 6) + (tx << 2)];
        double a0 = ar[0], a1 = ar[1], a2 = ar[2], a3 = ar[3];
        double b0 = br[0], b1 = br[1], b2 = br[2], b3 = br[3];
        acc[0][0] += a0 * b0; acc[0][1] += a0 * b1; acc[0][2] += a0 * b2; acc[0][3] += a0 * b3;
        acc[1][0] += a1 * b0; acc[1][1] += a1 * b1; acc[1][2] += a1 * b2; acc[1][3] += a1 * b3;
        acc[2][0] += a2 * b0; acc[2][1] += a2 * b1; acc[2][2] += a2 * b2; acc[2][3] += a2 * b3;
        acc[3][0] += a3 * b0; acc[3][1] += a3 * b1; acc[3][2] += a3 * b2; acc[3][3] += a3 * b3;
      }
    }
  }
  __syncthreads();
  double* xs = (double*)smraw;
  float* hwS = (float*)(smraw + 64 * 65 * 8);
  #pragma unroll
  for (int i = 0; i < 4; ++i) {
    int px = (ty << 2) + i;
    #pragma unroll
    for (int j = 0; j < 4; ++j) {
      int oc = (tx << 2) + j;
      double v = acc[i][j] + (double)conv_b[oc0 + oc];
      xs[px * 65 + oc] = v > 0.0 ? v : 0.0;
    }
  }
  for (int e = tid; e < 54 * 64; e += 256) {
    int o = e >> 6, ocl = e & 63;
    hwS[e] = (o < 18) ? cls_w[(o << 9) + oc0 + ocl]
                      : reg_w[((o - 18) << 9) + oc0 + ocl];
  }
  __syncthreads();
  int pixbase = (h << 7) + w0;
  for (int e = tid; e < 54 * 64; e += 256) {
    int px = e & 63, o = e >> 6;
    const double* xr = &xs[px * 65];
    const float* hr = &hwS[o << 6];
    double s = 0.0;
    #pragma unroll
    for (int j = 0; j < 64; ++j) s += xr[j] * (double)hr[j];
    atomicAdd(&predacc[(pixbase + px) * 54 + o], s);
  }
}

// per-anchor: heads bias, outputs, anchors, make_roi, score, sort entry
__global__ __launch_bounds__(256) void anchor_k(
    const double* __restrict__ predacc, const float* __restrict__ cls_b,
    const float* __restrict__ reg_b, float* __restrict__ out,
    double* __restrict__ roi_all, double* __restrict__ scores_d,
    ulonglong2* __restrict__ sortb)
{
  #pragma clang fp contract(off)
  int a = blockIdx.x * 256 + threadIdx.x;
  if (a >= NSORT) return;
  if (a >= NANC) {
    sortb[a] = make_ulonglong2(0xFFF0000000000000ULL, 0xFFFFFFFFULL);
    return;
  }
  int pix = a / 9;
  int k = a - pix * 9;
  int h = pix >> 7, wq = pix & 127;
  const double* pa = &predacc[pix * 54];
  double c0 = pa[2 * k] + (double)cls_b[2 * k];
  double c1 = pa[2 * k + 1] + (double)cls_b[2 * k + 1];
  double d0 = pa[18 + 4 * k + 0] + (double)reg_b[4 * k + 0];
  double d1 = pa[18 + 4 * k + 1] + (double)reg_b[4 * k + 1];
  double d2 = pa[18 + 4 * k + 2] + (double)reg_b[4 * k + 2];
  double d3 = pa[18 + 4 * k + 3] + (double)reg_b[4 * k + 3];
  out[OFF_CLS + a * 2 + 0] = (float)c0;
  out[OFF_CLS + a * 2 + 1] = (float)c1;
  out[OFF_REG + a * 4 + 0] = (float)d0;
  out[OFF_REG + a * 4 + 1] = (float)d1;
  out[OFF_REG + a * 4 + 2] = (float)d2;
  out[OFF_REG + a * 4 + 3] = (float)d3;
  int ir = k / 3, is = k - ir * 3;
  double ratio = (ir == 0) ? 0.5 : (ir == 1 ? 1.0 : 2.0);
  double asz = (is == 0) ? 8.0 : (is == 1 ? 16.0 : 32.0);
  double sq = sqrt(ratio);
  double wa = (16.0 * asz) / sq;
  double ha = (16.0 * asz) * sq;
  double cx = (h + 0.5) * 16.0;
  double cy = (wq + 0.5) * 16.0;
  double A0 = (double)(float)rint(cx - wa * 0.5);
  double A1 = (double)(float)rint(cy - ha * 0.5);
  double A2 = (double)(float)rint(cx + wa * 0.5);
  double A3 = (double)(float)rint(cy + ha * 0.5);
  double aw = A2 - A0, ah = A3 - A1;
  double acx = A0 + aw * 0.5, acy = A1 + ah * 0.5;
  double ccx = d0 * aw + acx;
  double ccy = d1 * ah + acy;
  double wr = exp(d2) * aw;
  double hh = exp(d3) * ah;
  double r0 = ccx - wr * 0.5;
  double r1 = ccy - hh * 0.5;
  double r2 = ccx + wr * 0.5;
  double r3 = ccy + hh * 0.5;
  r0 = fmax(r0, 0.0); r1 = fmax(r1, 0.0); r2 = fmax(r2, 0.0); r3 = fmax(r3, 0.0);
  r3 = (r3 > 2048.0) ? 2047.0 : r3;
  r2 = (r2 > 2048.0) ? 2047.0 : r2;
  bool valid = ((r2 - r0) > 16.0) && ((r3 - r1) > 16.0);
  double score = valid ? c1 : -__builtin_huge_val();
  roi_all[a * 4 + 0] = r0;
  roi_all[a * 4 + 1] = r1;
  roi_all[a * 4 + 2] = r2;
  roi_all[a * 4 + 3] = r3;
  scores_d[a] = score;
  u64 u = (u64)__double_as_longlong(score);
  u64 m = (u >> 63) ? ~u : (u | 0x8000000000000000ULL);
  sortb[a] = make_ulonglong2(~m, (u64)a);
}

// ------------------------- radix-select top-6000 ----------------------------
__global__ __launch_bounds__(1024) void hist_k(const ulonglong2* __restrict__ sortb,
                                               unsigned* __restrict__ hist,
                                               const u64* __restrict__ selp,
                                               int pass) {
  __shared__ unsigned h[2048];
  int t = threadIdx.x;
  h[t] = 0; h[t + 1024] = 0;
  __syncthreads();
  const int SH[3] = {53, 42, 31};
  const u64 PM[3] = {0ULL, 0xFFE0000000000000ULL, 0xFFFFFC0000000000ULL};
  u64 pfx = selp[0];
  u64 pm = PM[pass];
  int sh = SH[pass];
  for (int e = blockIdx.x * 1024 + t; e < NSORT; e += gridDim.x * 1024) {
    u64 k = sortb[e].x;
    if ((k & pm) == pfx)
      atomicAdd(&h[(unsigned)((k >> sh) & 2047)], 1u);
  }
  __syncthreads();
  if (h[t]) atomicAdd(&hist[t], h[t]);
  if (h[t + 1024]) atomicAdd(&hist[t + 1024], h[t + 1024]);
}

__global__ __launch_bounds__(1024) void scan_k(unsigned* hist, u64* selp, int pass) {
  __shared__ unsigned h[2048];
  int t = threadIdx.x;
  h[t] = hist[t]; h[t + 1024] = hist[t + 1024];
  hist[t] = 0; hist[t + 1024] = 0;
  __syncthreads();
  if (t == 0) {
    const int SH[3] = {53, 42, 31};
    u64 cum = selp[1];
    u64 pfx = selp[0];
    int b = 0;
    for (; b < 2047; ++b) {
      if (cum + h[b] >= (u64)TOPN) break;
      cum += h[b];
    }
    selp[0] = pfx | ((u64)b << SH[pass]);
    selp[1] = cum;
  }
}

__global__ __launch_bounds__(1024) void compact_k(
    const ulonglong2* __restrict__ sortb, const u64* __restrict__ selp,
    ulonglong2* __restrict__ cand, ulonglong2* __restrict__ bcand,
    unsigned* __restrict__ cnt) {
  u64 pfx = selp[0];
  const u64 M33 = 0xFFFFFFFF80000000ULL;
  for (int e = blockIdx.x * 1024 + threadIdx.x; e < NSORT; e += gridDim.x * 1024) {
    ulonglong2 v = sortb[e];
    u64 top = v.x & M33;
    if (top < pfx) {
      unsigned p = atomicAdd(&cnt[0], 1u);
      if (p < NCAND) cand[p] = v;
    } else if (top == pfx) {
      unsigned p = atomicAdd(&cnt[1], 1u);
      if (p < NBCAP) bcand[p] = v;
    }
  }
}

// ----- fused: fill + single-block LDS bitonic sort + box gather + rem init --
__device__ __forceinline__ bool sless(ulonglong2 A, ulonglong2 B) {
  return (A.x < B.x) || (A.x == B.x && A.y < B.y);
}

__global__ __launch_bounds__(1024) void sortprep_k(
    const ulonglong2* __restrict__ cand, const ulonglong2* __restrict__ bcand,
    const unsigned* __restrict__ cnt, const double* __restrict__ roi_all,
    const double* __restrict__ scores_d, double* __restrict__ boxes,
    u64* __restrict__ removed)
{
  extern __shared__ ulonglong2 s[];   // 8192 * 16B = 128 KB dynamic LDS
  int t = threadIdx.x;
  unsigned ci = cnt[0]; if (ci > NCAND) ci = NCAND;
  unsigned cb = cnt[1]; if (cb > NBCAP) cb = NBCAP;
  #pragma unroll
  for (int i = 0; i < 8; ++i) {
    int p = t + (i << 10);
    ulonglong2 v;
    if (p < (int)ci) v = cand[p];
    else if (p < (int)(ci + cb)) v = bcand[p - ci];
    else v = make_ulonglong2(~0ULL, ~0ULL);
    s[p] = v;
  }
  __syncthreads();
  for (int k = 2; k <= NCAND; k <<= 1) {
    for (int j = k >> 1; j >= 1; j >>= 1) {
      #pragma unroll
      for (int q = 0; q < 4; ++q) {
        int p = t + (q << 10);
        int li = ((p & ~(j - 1)) << 1) | (p & (j - 1));
        int pa = li | j;
        bool asc = ((li & k) == 0);
        ulonglong2 A = s[li], B = s[pa];
        bool sw = asc ? sless(B, A) : sless(A, B);
        if (sw) { s[li] = B; s[pa] = A; }
      }
      __syncthreads();
    }
  }
  // gather boxes for top-6000 directly from sorted LDS
  for (int i = t; i < TOPN; i += 1024) {
    unsigned idx = (unsigned)s[i].y;
    double b0 = 0, b1 = 0, b2 = 0, b3 = 0;
    if (idx < NANC) {
      b0 = roi_all[idx * 4 + 0];
      b1 = roi_all[idx * 4 + 1];
      b2 = roi_all[idx * 4 + 2];
      b3 = roi_all[idx * 4 + 3];
    }
    boxes[i * 4 + 0] = b0; boxes[i * 4 + 1] = b1;
    boxes[i * 4 + 2] = b2; boxes[i * 4 + 3] = b3;
  }
  if (t < NWORDS) {
    u64 wdd = (t == NWORDS - 1) ? 0xFFFF000000000000ULL : 0ULL;
    for (int b = 0; b < 64; ++b) {
      int i = t * 64 + b;
      if (i >= TOPN) break;
      unsigned idx = (unsigned)s[i].y;
      bool dead = true;
      if (idx < NANC) dead = isinf(scores_d[idx]);
      if (dead) wdd |= (1ULL << b);
    }
    removed[t] = wdd;
  }
}

// suppression bitmask (triangular: only words w >= chunk(i) are written/read)
__global__ __launch_bounds__(256) void mask_k(const double* __restrict__ boxes,
                                              u64* __restrict__ mask) {
  #pragma clang fp contract(off)
  int gw = (blockIdx.x * 256 + threadIdx.x) >> 6;
  int lane = threadIdx.x & 63;
  int i = gw / NWORDS, wj = gw - i * NWORDS;
  if (i >= TOPN) return;
  if (wj < (i >> 6)) return;
  double ix1 = boxes[i * 4 + 0], iy1 = boxes[i * 4 + 1];
  double ix2 = boxes[i * 4 + 2], iy2 = boxes[i * 4 + 3];
  double tx1 = trunc(ix1), ty1 = trunc(iy1), tx2 = trunc(ix2), ty2 = trunc(iy2);
  double gminx = fmin(tx1, tx2), gmaxx = fmax(tx1, tx2);
  double gminy = fmin(ty1, ty2), gmaxy = fmax(ty1, ty2);
  double gw_ = trunc(ix2 - ix1), gh_ = trunc(iy2 - iy1);
  int j = wj * 64 + lane;
  bool pred = false;
  if (j < TOPN && j > i) {
    double jx1 = boxes[j * 4 + 0], jy1 = boxes[j * 4 + 1];
    double jx2 = boxes[j * 4 + 2], jy2 = boxes[j * 4 + 3];
    double aw = jx2 - jx1, ah = jy2 - jy1;
    double aminx = fmin(jx1, jx2), amaxx = fmax(jx1, jx2);
    double aminy = fmin(jy1, jy2), amaxy = fmax(jy1, jy2);
    double iw = fmin(aminx, gminx) + aw + gw_ - fmax(amaxx, gmaxx);
    iw = fmax(iw, 0.0);
    double ih = fmin(aminy, gminy) + ah + gh_ - fmax(amaxy, gmaxy);
    ih = fmax(ih, 0.0);
    double inter = iw * ih;
    double uni = aw * ah + gw_ * gh_ - inter;
    pred = (inter / uni >= 0.7);
  }
  u64 bal = __ballot(pred);
  if (lane == 0) mask[(size_t)i * NWORDS + wj] = bal;
}

// chunked greedy suppression
__global__ __launch_bounds__(1024) void nms_chunk_k(const u64* __restrict__ mask,
                                                    u64* removed_g) {
  __shared__ u64 rem[NWORDS];
  __shared__ u64 aliveSh;
  int t = threadIdx.x;
  int lane = t & 63;
  int wvid = t >> 6;
  if (t < NWORDS) rem[t] = removed_g[t];
  __syncthreads();
  for (int c = 0; c < NWORDS; ++c) {
    if (wvid == 0) {
      int i = c * 64 + lane;
      u64 diag = (i < TOPN) ? mask[(size_t)i * NWORDS + c] : 0ULL;
      u64 local = rem[c];
      #pragma unroll 1
      for (int j = 0; j < 64; ++j) {
        u64 dj = __shfl(diag, j);
        if (!((local >> j) & 1ULL)) local |= dj;
      }
      if (lane == 0) { rem[c] = local; aliveSh = ~local; }
    }
    __syncthreads();
    u64 alive = aliveSh;
    int nw = NWORDS - 1 - c;
    if (nw > 0 && alive) {
      int npairs = 64 * nw;
      for (int p = t; p < npairs; p += 1024) {
        int j = p / nw;
        int w = c + 1 + (p - j * nw);
        if ((alive >> j) & 1ULL) {
          int i = c * 64 + j;
          if (i < TOPN) {
            u64 v = mask[(size_t)i * NWORDS + w];
            if (v) atomicOr(&rem[w], v);
          }
        }
      }
    }
    __syncthreads();
  }
  if (t < NWORDS) removed_g[t] = rem[t];
}

__global__ __launch_bounds__(256) void out_k(const u64* __restrict__ removed,
                                             const double* __restrict__ boxes,
                                             float* __restrict__ out) {
  __shared__ int pref[NWORDS + 1];
  __shared__ u64 keepw[NWORDS];
  int t = threadIdx.x;
  for (int i = t; i < NOUT * 4; i += 256) out[i] = 0.0f;
  if (t < NWORDS) keepw[t] = ~removed[t];
  __syncthreads();
  if (t == 0) {
    int s = 0;
    for (int w = 0; w < NWORDS; ++w) { pref[w] = s; s += __popcll(keepw[w]); }
    pref[NWORDS] = s;
  }
  __syncthreads();
  for (int i = t; i < TOPN; i += 256) {
    u64 kw = keepw[i >> 6];
    if ((kw >> (i & 63)) & 1ULL) {
      int rank = pref[i >> 6] + __popcll(kw & ((1ULL << (i & 63)) - 1ULL));
      if (rank < NOUT) {
        out[rank * 4 + 0] = (float)boxes[i * 4 + 0];
        out[rank * 4 + 1] = (float)boxes[i * 4 + 1];
        out[rank * 4 + 2] = (float)boxes[i * 4 + 2];
        out[rank * 4 + 3] = (float)boxes[i * 4 + 3];
      }
    }
  }
}

extern "C" void kernel_launch(void* const* d_in, const int* in_sizes, int n_in,
                              void* d_out, int out_size, void* d_ws, size_t ws_size,
                              hipStream_t stream) {
  const float* feat = (const float*)d_in[0];
  const float* c3w = (const float*)d_in[1];
  const float* c3b = (const float*)d_in[2];
  const float* clw = (const float*)d_in[3];
  const float* clb = (const float*)d_in[4];
  const float* rgw = (const float*)d_in[5];
  const float* rgb = (const float*)d_in[6];
  float* out = (float*)d_out;
  char* ws = (char*)d_ws;
  size_t off = 0;
  auto alloc = [&](size_t bytes) {
    size_t o = off;
    off = (off + bytes + 255) & ~(size_t)255;
    return o;
  };
  double* predacc = (double*)(ws + alloc(16384ULL * 54 * 8));     // 7.08 MB
  double* flagd = (double*)(ws + alloc(256));
  float* wt = (float*)(ws + alloc(2359296ULL * 4));               // 9.44 MB
  double* roi_all = (double*)(ws + alloc((size_t)NANC * 4 * 8));  // 4.72 MB
  double* scores_d = (double*)(ws + alloc((size_t)NANC * 8));     // 1.18 MB
  ulonglong2* sortb = (ulonglong2*)(ws + alloc((size_t)NSORT * 16)); // 4.19 MB
  double* boxes = (double*)(ws + alloc((size_t)TOPN * 4 * 8));    // 0.19 MB
  u64* mask = (u64*)(ws + alloc((size_t)TOPN * NWORDS * 8));      // 4.51 MB
  u64* removed = (u64*)(ws + alloc(NWORDS * 8));
  double* xraw = (double*)(ws + alloc(4 * 512 * 8));              // 16 KB
  unsigned* hist = (unsigned*)(ws + alloc(2048 * 4));             // 8 KB
  u64* selp = (u64*)(ws + alloc(256));
  unsigned* cntb = (unsigned*)(ws + alloc(256));
  ulonglong2* cand = (ulonglong2*)(ws + alloc((size_t)NCAND * 16));   // 128 KB
  ulonglong2* bcand = (ulonglong2*)(ws + alloc((size_t)NBCAP * 16));  // 32 KB
  (void)ws_size; (void)out_size; (void)in_sizes; (void)n_in;

  const int NPRED = 16384 * 54;
  hipLaunchKernelGGL(zero3_k, dim3((NPRED + 32 + 2048 + 255) / 256), dim3(256), 0,
                     stream, predacc, NPRED + 32, xraw, 2048, hist, selp, cntb);
  hipLaunchKernelGGL(wtrans_k, dim3(512), dim3(256), 0, stream, c3w, wt);
  hipLaunchKernelGGL(conv_mfma_k, dim3(2048), dim3(256), 0, stream,
                     feat, wt, c3b, clw, rgw, predacc);
  // verify MFMA result at 4 probe pixels; gated VALU fallback
  hipLaunchKernelGGL(chk_x_k, dim3(256), dim3(256), 0, stream, feat, c3w, xraw);
  hipLaunchKernelGGL(chk_cmp_k, dim3(1), dim3(256), 0, stream,
                     xraw, c3b, clw, rgw, predacc, flagd);
  hipLaunchKernelGGL(rezero_k, dim3((NPRED + 255) / 256), dim3(256), 0, stream,
                     flagd, predacc, NPRED);
  hipLaunchKernelGGL(conv_fb_k, dim3(2048), dim3(256), 0, stream,
                     flagd, feat, wt, c3b, clw, rgw, predacc);
  hipLaunchKernelGGL(anchor_k, dim3(NSORT / 256), dim3(256), 0, stream,
                     predacc, clb, rgb, out, roi_all, scores_d, sortb);
  // radix-select top-6000
  for (int pass = 0; pass < 3; ++pass) {
    hipLaunchKernelGGL(hist_k, dim3(128), dim3(1024), 0, stream,
                       sortb, hist, selp, pass);
    hipLaunchKernelGGL(scan_k, dim3(1), dim3(1024), 0, stream, hist, selp, pass);
  }
  hipLaunchKernelGGL(compact_k, dim3(128), dim3(1024), 0, stream,
                     sortb, selp, cand, bcand, cntb);
  // fused fill + sort(8192) + box-gather + removed-init
  hipLaunchKernelGGL(sortprep_k, dim3(1), dim3(1024), NCAND * 16, stream,
                     cand, bcand, cntb, roi_all, scores_d, boxes, removed);
  // NMS
  hipLaunchKernelGGL(mask_k, dim3(TOPN * NWORDS / 4), dim3(256), 0, stream,
                     boxes, mask);
  hipLaunchKernelGGL(nms_chunk_k, dim3(1), dim3(1024), 0, stream, mask, removed);
  hipLaunchKernelGGL(out_k, dim3(1), dim3(256), 0, stream, removed, boxes, out);
}

// Round 10
// 2266.828 us; speedup vs baseline: 1.2741x; 1.0494x over previous
//
#include <hip/hip_runtime.h>

#define HF 128
#define WF 128
#define KANC 9
#define NANC (HF*WF*KANC)      // 147456
#define NSORT 262144
#define TOPN 6000
#define NWORDS 94              // ceil(6000/64)
#define NOUT 2000
#define OFF_CLS 8000
#define OFF_REG 302912
#define NCAND 8192
#define NBCAP 2048

typedef unsigned long long u64;
typedef double d4 __attribute__((ext_vector_type(4)));
typedef const __attribute__((address_space(1))) void* gas1;
typedef __attribute__((address_space(3))) void* las3;

__global__ __launch_bounds__(256) void zinit_k(double* p1, int n1,
                                               unsigned* hist, u64* selp,
                                               unsigned* cnt) {
  int i = blockIdx.x * 256 + threadIdx.x;
  if (i < n1) p1[i] = 0.0;
  if (i < 2048) hist[i] = 0;
  if (i == 0) { selp[0] = 0; selp[1] = 0; cnt[0] = 0; cnt[1] = 0; }
}

// conv3_w [oc][ic][kh][kw] -> wt [tap][ic][oc], LDS-tiled transpose.
__global__ __launch_bounds__(256) void wtrans_k(const float* __restrict__ w,
                                                float* __restrict__ wt) {
  __shared__ float ld[64 * 73];
  int t = threadIdx.x;
  int ocg = blockIdx.x & 7, icg = blockIdx.x >> 3;
  int oc0 = ocg << 6, ic0 = icg << 3;
  #pragma unroll
  for (int rep = 0; rep < 18; ++rep) {
    int idx = rep * 256 + t;            // 0..4607
    int row = idx / 72, col = idx - row * 72;
    ld[row * 73 + col] = w[(size_t)(oc0 + row) * 4608 + ic0 * 9 + col];
  }
  __syncthreads();
  #pragma unroll
  for (int rep = 0; rep < 18; ++rep) {
    int idx = rep * 256 + t;
    int pair = idx >> 6, oc = idx & 63;
    int tap = pair % 9, ic = pair / 9;
    wt[(size_t)tap * 262144 + (size_t)(ic0 + ic) * 512 + oc0 + oc] =
        ld[oc * 73 + ic * 9 + tap];
  }
}

// ---------------------------------------------------------------------------
// conv3x3(512->512) as fp64-MFMA GEMM, heads fused in epilogue.
// 64px x 64oc tile, 32KB LDS -> 4 blocks/CU; grid 2048 = 2 exact phases.
// Verified (counters+absmax) R9; UNCHANGED this round.
// ---------------------------------------------------------------------------
#define BKC 32
#define NCHUNK 144

__global__ __launch_bounds__(256, 4) void conv_mfma_k(
    const float* __restrict__ feat, const float* __restrict__ wt,
    const float* __restrict__ conv_b, const float* __restrict__ cls_w,
    const float* __restrict__ reg_w, double* __restrict__ predacc)
{
  __shared__ __align__(16) char smraw[32768];
  float* AsB = (float*)smraw;                     // [2][32*64]
  float* BsB = (float*)(smraw + 2 * 2048 * 4);    // [2][32*64]
  int tid = threadIdx.x;
  int bid = blockIdx.x;
  int pt = bid & 255, ot = bid >> 8;              // ot 0..7
  int h = pt >> 1, w0 = (pt & 1) << 6;
  int oc0 = ot << 6;
  int wv = tid >> 6, l = tid & 63;
  int wr = wv >> 1, wc = wv & 1;                  // 2x2 waves of 32px x 32oc
  int lg = l >> 4, lr = l & 15;

  d4 acc[2][2];
  #pragma unroll
  for (int t = 0; t < 2; ++t)
    #pragma unroll
    for (int u = 0; u < 2; ++u) acc[t][u] = (d4)0.0;

  float4 areg[2];

  auto gloadA = [&](int c) {
    int tap = c >> 4, ic0 = (c & 15) << 5;
    int kh = tap / 3 - 1, kw = tap % 3 - 1;
    int hp = h + kh;
    bool okh = ((unsigned)hp < 128u);
    #pragma unroll
    for (int i = 0; i < 2; ++i) {
      int q = tid + (i << 8);
      int r = q >> 4, c0 = (q & 15) << 2;
      float v0 = 0.f, v1 = 0.f, v2 = 0.f, v3 = 0.f;
      const float* src = &feat[((ic0 + r) << 14) + (hp << 7)];
      int wp = w0 + c0 + kw;
      if (okh) {
        if ((unsigned)(wp + 0) < 128u) v0 = src[wp + 0];
        if ((unsigned)(wp + 1) < 128u) v1 = src[wp + 1];
        if ((unsigned)(wp + 2) < 128u) v2 = src[wp + 2];
        if ((unsigned)(wp + 3) < 128u) v3 = src[wp + 3];
      }
      areg[i] = make_float4(v0, v1, v2, v3);
    }
  };
  auto gloadB_lds = [&](int c, int buf) {
    float* B = BsB + buf * 2048;
    #pragma unroll
    for (int i = 0; i < 2; ++i) {
      int q = tid + (i << 8);
      int r = q >> 4, c0 = (q & 15) << 2;
      const float* src =
          &wt[(size_t)((c << 5) + r) * 512 + oc0 + (c0 ^ ((r & 1) << 4))];
      __builtin_amdgcn_global_load_lds((gas1)src, (las3)&B[q << 2], 16, 0, 0);
    }
  };
  auto dswriteA = [&](int buf) {
    float* A = AsB + buf * 2048;
    #pragma unroll
    for (int i = 0; i < 2; ++i) {
      int q = tid + (i << 8);
      int r = q >> 4, c0 = (q & 15) << 2;
      *(float4*)&A[(r << 6) + (c0 ^ ((r & 1) << 4))] = areg[i];
    }
  };
  auto compute = [&](int buf) {
    const float* A = AsB + buf * 2048;
    const float* B = BsB + buf * 2048;
    #pragma unroll
    for (int k4 = 0; k4 < BKC; k4 += 4) {
      int krow = k4 + lg;
      int sw = (krow & 1) << 4;
      double a0 = (double)A[(krow << 6) + (((wr << 5) + lr) ^ sw)];
      double a1 = (double)A[(krow << 6) + (((wr << 5) + 16 + lr) ^ sw)];
      double b0 = (double)B[(krow << 6) + (((wc << 5) + lr) ^ sw)];
      double b1 = (double)B[(krow << 6) + (((wc << 5) + 16 + lr) ^ sw)];
      acc[0][0] = __builtin_amdgcn_mfma_f64_16x16x4f64(a0, b0, acc[0][0], 0, 0, 0);
      acc[0][1] = __builtin_amdgcn_mfma_f64_16x16x4f64(a0, b1, acc[0][1], 0, 0, 0);
      acc[1][0] = __builtin_amdgcn_mfma_f64_16x16x4f64(a1, b0, acc[1][0], 0, 0, 0);
      acc[1][1] = __builtin_amdgcn_mfma_f64_16x16x4f64(a1, b1, acc[1][1], 0, 0, 0);
    }
  };

  gloadA(0);
  gloadB_lds(0, 0);
  dswriteA(0);
  for (int c = 0; c < NCHUNK; ++c) {
    __syncthreads();
    if (c + 1 < NCHUNK) {
      gloadB_lds(c + 1, (c + 1) & 1);
      gloadA(c + 1);
    }
    compute(c & 1);
    if (c + 1 < NCHUNK) dswriteA((c + 1) & 1);
  }

  // --- probe D fragment layout (post-loop; correct for any separable map) ---
  int rmap[4], cmap[4];
  {
    d4 z = (d4)0.0;
    double apr = (lg == 0) ? (double)lr : 0.0;
    double bpr = (lg == 0) ? 1.0 : 0.0;
    d4 dr = __builtin_amdgcn_mfma_f64_16x16x4f64(apr, bpr, z, 0, 0, 0);
    double apc = (lg == 0) ? 1.0 : 0.0;
    double bpc = (lg == 0) ? (double)lr : 0.0;
    d4 dc = __builtin_amdgcn_mfma_f64_16x16x4f64(apc, bpc, z, 0, 0, 0);
    #pragma unroll
    for (int r = 0; r < 4; ++r) { rmap[r] = (int)dr[r]; cmap[r] = (int)dc[r]; }
  }

  // ---- epilogue: two 32-px halves: bias+relu -> xs, head dots, atomics ----
  double* xs = (double*)smraw;                  // [32][65] doubles = 16640 B
  float* hwS = (float*)(smraw + 32 * 65 * 8);   // [54][64] floats  = 13824 B
  __syncthreads();
  for (int e = tid; e < 54 * 64; e += 256) {
    int o = e >> 6, j = e & 63;
    hwS[e] = (o < 18) ? cls_w[(o << 9) + oc0 + j]
                      : reg_w[((o - 18) << 9) + oc0 + j];
  }
  int pixbase = (h << 7) + w0;
  #pragma unroll
  for (int ph = 0; ph < 2; ++ph) {
    if (wr == ph) {
      #pragma unroll
      for (int t = 0; t < 2; ++t) {
        #pragma unroll
        for (int u = 0; u < 2; ++u) {
          #pragma unroll
          for (int r = 0; r < 4; ++r) {
            int ocl = (wc << 5) + (u << 4) + cmap[r];
            int pxl = (t << 4) + rmap[r];
            double v = acc[t][u][r] + (double)conv_b[oc0 + ocl];
            xs[pxl * 65 + ocl] = (v > 0.0) ? v : 0.0;
          }
        }
      }
    }
    __syncthreads();
    #pragma unroll
    for (int it = 0; it < 7; ++it) {
      int e = tid + (it << 8);
      if (e < 54 * 32) {
        int o = e >> 5, px = e & 31;
        const double* xr = &xs[px * 65];
        const float* hr = &hwS[o << 6];
        double s = 0.0;
        #pragma unroll
        for (int j = 0; j < 64; ++j) s += xr[j] * (double)hr[j];
        atomicAdd(&predacc[(size_t)(pixbase + (ph << 5) + px) * 54 + o], s);
      }
    }
    __syncthreads();
  }
}

// per-anchor: heads bias, outputs, anchors, make_roi, score, sort entry
__global__ __launch_bounds__(256) void anchor_k(
    const double* __restrict__ predacc, const float* __restrict__ cls_b,
    const float* __restrict__ reg_b, float* __restrict__ out,
    double* __restrict__ roi_all, double* __restrict__ scores_d,
    ulonglong2* __restrict__ sortb)
{
  #pragma clang fp contract(off)
  int a = blockIdx.x * 256 + threadIdx.x;
  if (a >= NSORT) return;
  if (a >= NANC) {
    sortb[a] = make_ulonglong2(0xFFF0000000000000ULL, 0xFFFFFFFFULL);
    return;
  }
  int pix = a / 9;
  int k = a - pix * 9;
  int h = pix >> 7, wq = pix & 127;
  const double* pa = &predacc[pix * 54];
  double c0 = pa[2 * k] + (double)cls_b[2 * k];
  double c1 = pa[2 * k + 1] + (double)cls_b[2 * k + 1];
  double d0 = pa[18 + 4 * k + 0] + (double)reg_b[4 * k + 0];
  double d1 = pa[18 + 4 * k + 1] + (double)reg_b[4 * k + 1];
  double d2 = pa[18 + 4 * k + 2] + (double)reg_b[4 * k + 2];
  double d3 = pa[18 + 4 * k + 3] + (double)reg_b[4 * k + 3];
  out[OFF_CLS + a * 2 + 0] = (float)c0;
  out[OFF_CLS + a * 2 + 1] = (float)c1;
  out[OFF_REG + a * 4 + 0] = (float)d0;
  out[OFF_REG + a * 4 + 1] = (float)d1;
  out[OFF_REG + a * 4 + 2] = (float)d2;
  out[OFF_REG + a * 4 + 3] = (float)d3;
  int ir = k / 3, is = k - ir * 3;
  double ratio = (ir == 0) ? 0.5 : (ir == 1 ? 1.0 : 2.0);
  double asz = (is == 0) ? 8.0 : (is == 1 ? 16.0 : 32.0);
  double sq = sqrt(ratio);
  double wa = (16.0 * asz) / sq;
  double ha = (16.0 * asz) * sq;
  double cx = (h + 0.5) * 16.0;
  double cy = (wq + 0.5) * 16.0;
  double A0 = (double)(float)rint(cx - wa * 0.5);
  double A1 = (double)(float)rint(cy - ha * 0.5);
  double A2 = (double)(float)rint(cx + wa * 0.5);
  double A3 = (double)(float)rint(cy + ha * 0.5);
  double aw = A2 - A0, ah = A3 - A1;
  double acx = A0 + aw * 0.5, acy = A1 + ah * 0.5;
  double ccx = d0 * aw + acx;
  double ccy = d1 * ah + acy;
  double wr = exp(d2) * aw;
  double hh = exp(d3) * ah;
  double r0 = ccx - wr * 0.5;
  double r1 = ccy - hh * 0.5;
  double r2 = ccx + wr * 0.5;
  double r3 = ccy + hh * 0.5;
  r0 = fmax(r0, 0.0); r1 = fmax(r1, 0.0); r2 = fmax(r2, 0.0); r3 = fmax(r3, 0.0);
  r3 = (r3 > 2048.0) ? 2047.0 : r3;
  r2 = (r2 > 2048.0) ? 2047.0 : r2;
  bool valid = ((r2 - r0) > 16.0) && ((r3 - r1) > 16.0);
  double score = valid ? c1 : -__builtin_huge_val();
  roi_all[a * 4 + 0] = r0;
  roi_all[a * 4 + 1] = r1;
  roi_all[a * 4 + 2] = r2;
  roi_all[a * 4 + 3] = r3;
  scores_d[a] = score;
  u64 u = (u64)__double_as_longlong(score);
  u64 m = (u >> 63) ? ~u : (u | 0x8000000000000000ULL);
  sortb[a] = make_ulonglong2(~m, (u64)a);
}

// ------------------------- radix-select top-6000 ----------------------------
__global__ __launch_bounds__(1024) void hist_k(const ulonglong2* __restrict__ sortb,
                                               unsigned* __restrict__ hist,
                                               const u64* __restrict__ selp,
                                               int pass) {
  __shared__ unsigned h[2048];
  int t = threadIdx.x;
  h[t] = 0; h[t + 1024] = 0;
  __syncthreads();
  const int SH[3] = {53, 42, 31};
  const u64 PM[3] = {0ULL, 0xFFE0000000000000ULL, 0xFFFFFC0000000000ULL};
  u64 pfx = selp[0];
  u64 pm = PM[pass];
  int sh = SH[pass];
  for (int e = blockIdx.x * 1024 + t; e < NSORT; e += gridDim.x * 1024) {
    u64 k = sortb[e].x;
    if ((k & pm) == pfx)
      atomicAdd(&h[(unsigned)((k >> sh) & 2047)], 1u);
  }
  __syncthreads();
  if (h[t]) atomicAdd(&hist[t], h[t]);
  if (h[t + 1024]) atomicAdd(&hist[t + 1024], h[t + 1024]);
}

__global__ __launch_bounds__(1024) void scan_k(unsigned* hist, u64* selp, int pass) {
  __shared__ unsigned h[2048];
  int t = threadIdx.x;
  h[t] = hist[t]; h[t + 1024] = hist[t + 1024];
  hist[t] = 0; hist[t + 1024] = 0;
  __syncthreads();
  if (t == 0) {
    const int SH[3] = {53, 42, 31};
    u64 cum = selp[1];
    u64 pfx = selp[0];
    int b = 0;
    for (; b < 2047; ++b) {
      if (cum + h[b] >= (u64)TOPN) break;
      cum += h[b];
    }
    selp[0] = pfx | ((u64)b << SH[pass]);
    selp[1] = cum;
  }
}

__global__ __launch_bounds__(1024) void compact_k(
    const ulonglong2* __restrict__ sortb, const u64* __restrict__ selp,
    ulonglong2* __restrict__ cand, ulonglong2* __restrict__ bcand,
    unsigned* __restrict__ cnt) {
  u64 pfx = selp[0];
  const u64 M33 = 0xFFFFFFFF80000000ULL;
  for (int e = blockIdx.x * 1024 + threadIdx.x; e < NSORT; e += gridDim.x * 1024) {
    ulonglong2 v = sortb[e];
    u64 top = v.x & M33;
    if (top < pfx) {
      unsigned p = atomicAdd(&cnt[0], 1u);
      if (p < NCAND) cand[p] = v;
    } else if (top == pfx) {
      unsigned p = atomicAdd(&cnt[1], 1u);
      if (p < NBCAP) bcand[p] = v;
    }
  }
}

// ---------------- parallel bitonic sort of 8192 (4 blocks) ------------------
__device__ __forceinline__ bool sless(ulonglong2 A, ulonglong2 B) {
  return (A.x < B.x) || (A.x == B.x && A.y < B.y);
}

// fill + local sort of 2048 (alternating direction per bitonic)
__global__ __launch_bounds__(1024) void sortloc_k(
    ulonglong2* cand, const ulonglong2* __restrict__ bcand,
    const unsigned* __restrict__ cnt) {
  __shared__ ulonglong2 s[2048];
  int t = threadIdx.x;
  int base = blockIdx.x * 2048;
  unsigned ci = cnt[0]; if (ci > NCAND) ci = NCAND;
  unsigned cb = cnt[1]; if (cb > NBCAP) cb = NBCAP;
  #pragma unroll
  for (int i = 0; i < 2; ++i) {
    int p = base + t + (i << 10);
    ulonglong2 v;
    if (p < (int)ci) v = cand[p];
    else if (p < (int)(ci + cb)) v = bcand[p - ci];
    else v = make_ulonglong2(~0ULL, ~0ULL);
    s[t + (i << 10)] = v;
  }
  __syncthreads();
  for (int k = 2; k <= 2048; k <<= 1)
    for (int j = k >> 1; j >= 1; j >>= 1) {
      int li = ((t & ~(j - 1)) << 1) | (t & (j - 1));
      int pa = li | j;
      bool asc = (((base + li) & k) == 0);
      ulonglong2 A = s[li], B = s[pa];
      bool sw = asc ? sless(B, A) : sless(A, B);
      if (sw) { s[li] = B; s[pa] = A; }
      __syncthreads();
    }
  cand[base + t] = s[t];
  cand[base + t + 1024] = s[t + 1024];
}

__global__ __launch_bounds__(256) void bitonic_global(ulonglong2* d, int k, int j) {
  int t = blockIdx.x * 256 + threadIdx.x;
  int i = ((t & ~(j - 1)) << 1) | (t & (j - 1));
  int p = i | j;
  bool asc = ((i & k) == 0);
  ulonglong2 A = d[i], B = d[p];
  bool sw = asc ? sless(B, A) : sless(A, B);
  if (sw) { d[i] = B; d[p] = A; }
}

__global__ __launch_bounds__(1024) void bitonic_lm(ulonglong2* d, int k) {
  __shared__ ulonglong2 s[2048];
  int t = threadIdx.x;
  int base = blockIdx.x * 2048;
  bool asc = ((base & k) == 0);
  s[t] = d[base + t];
  s[t + 1024] = d[base + t + 1024];
  __syncthreads();
  for (int j = 1024; j >= 1; j >>= 1) {
    int li = ((t & ~(j - 1)) << 1) | (t & (j - 1));
    int pa = li | j;
    ulonglong2 A = s[li], B = s[pa];
    bool sw = asc ? sless(B, A) : sless(A, B);
    if (sw) { s[li] = B; s[pa] = A; }
    __syncthreads();
  }
  d[base + t] = s[t];
  d[base + t + 1024] = s[t + 1024];
}

// final local merge (k=8192, ascending) fused with box gather + removed init
__global__ __launch_bounds__(1024) void sortfin_k(
    ulonglong2* d, const double* __restrict__ roi_all,
    const double* __restrict__ scores_d, double* __restrict__ boxes,
    u64* __restrict__ removed) {
  __shared__ ulonglong2 s[2048];
  int t = threadIdx.x;
  int base = blockIdx.x * 2048;
  s[t] = d[base + t];
  s[t + 1024] = d[base + t + 1024];
  __syncthreads();
  for (int j = 1024; j >= 1; j >>= 1) {
    int li = ((t & ~(j - 1)) << 1) | (t & (j - 1));
    int pa = li | j;
    ulonglong2 A = s[li], B = s[pa];
    if (sless(B, A)) { s[li] = B; s[pa] = A; }   // k=8192: all ascending
    __syncthreads();
  }
  #pragma unroll
  for (int q = 0; q < 2; ++q) {
    int li = t + (q << 10);
    int i = base + li;
    if (i < TOPN) {
      unsigned idx = (unsigned)s[li].y;
      double b0 = 0, b1 = 0, b2 = 0, b3 = 0;
      if (idx < NANC) {
        b0 = roi_all[idx * 4 + 0];
        b1 = roi_all[idx * 4 + 1];
        b2 = roi_all[idx * 4 + 2];
        b3 = roi_all[idx * 4 + 3];
      }
      boxes[i * 4 + 0] = b0; boxes[i * 4 + 1] = b1;
      boxes[i * 4 + 2] = b2; boxes[i * 4 + 3] = b3;
    }
  }
  if (t < 32) {
    int w = (base >> 6) + t;
    if (w < NWORDS) {
      u64 wdd = (w == NWORDS - 1) ? 0xFFFF000000000000ULL : 0ULL;
      for (int b = 0; b < 64; ++b) {
        int i = w * 64 + b;
        if (i >= TOPN) break;
        unsigned idx = (unsigned)s[i - base].y;
        bool dead = true;
        if (idx < NANC) dead = isinf(scores_d[idx]);
        if (dead) wdd |= (1ULL << b);
      }
      removed[w] = wdd;
    }
  }
}

// suppression bitmask (triangular: only words w >= chunk(i) are written/read)
__global__ __launch_bounds__(256) void mask_k(const double* __restrict__ boxes,
                                              u64* __restrict__ mask) {
  #pragma clang fp contract(off)
  int gw = (blockIdx.x * 256 + threadIdx.x) >> 6;
  int lane = threadIdx.x & 63;
  int i = gw / NWORDS, wj = gw - i * NWORDS;
  if (i >= TOPN) return;
  if (wj < (i >> 6)) return;
  double ix1 = boxes[i * 4 + 0], iy1 = boxes[i * 4 + 1];
  double ix2 = boxes[i * 4 + 2], iy2 = boxes[i * 4 + 3];
  double tx1 = trunc(ix1), ty1 = trunc(iy1), tx2 = trunc(ix2), ty2 = trunc(iy2);
  double gminx = fmin(tx1, tx2), gmaxx = fmax(tx1, tx2);
  double gminy = fmin(ty1, ty2), gmaxy = fmax(ty1, ty2);
  double gw_ = trunc(ix2 - ix1), gh_ = trunc(iy2 - iy1);
  int j = wj * 64 + lane;
  bool pred = false;
  if (j < TOPN && j > i) {
    double jx1 = boxes[j * 4 + 0], jy1 = boxes[j * 4 + 1];
    double jx2 = boxes[j * 4 + 2], jy2 = boxes[j * 4 + 3];
    double aw = jx2 - jx1, ah = jy2 - jy1;
    double aminx = fmin(jx1, jx2), amaxx = fmax(jx1, jx2);
    double aminy = fmin(jy1, jy2), amaxy = fmax(jy1, jy2);
    double iw = fmin(aminx, gminx) + aw + gw_ - fmax(amaxx, gmaxx);
    iw = fmax(iw, 0.0);
    double ih = fmin(aminy, gminy) + ah + gh_ - fmax(amaxy, gmaxy);
    ih = fmax(ih, 0.0);
    double inter = iw * ih;
    double uni = aw * ah + gw_ * gh_ - inter;
    pred = (inter / uni >= 0.7);
  }
  u64 bal = __ballot(pred);
  if (lane == 0) mask[(size_t)i * NWORDS + wj] = bal;
}

// chunked greedy suppression fused with ranked output scatter
__global__ __launch_bounds__(1024) void nmsout_k(const u64* __restrict__ mask,
                                                 const u64* __restrict__ removed_g,
                                                 const double* __restrict__ boxes,
                                                 float* __restrict__ out) {
  __shared__ u64 rem[NWORDS];
  __shared__ u64 aliveSh;
  __shared__ int pref[NWORDS + 1];
  int t = threadIdx.x;
  int lane = t & 63;
  int wvid = t >> 6;
  if (t < NWORDS) rem[t] = removed_g[t];
  for (int i = t; i < NOUT * 4; i += 1024) out[i] = 0.0f;
  __syncthreads();
  for (int c = 0; c < NWORDS; ++c) {
    if (wvid == 0) {
      int i = c * 64 + lane;
      u64 diag = (i < TOPN) ? mask[(size_t)i * NWORDS + c] : 0ULL;
      u64 local = rem[c];
      #pragma unroll 1
      for (int j = 0; j < 64; ++j) {
        u64 dj = __shfl(diag, j);
        if (!((local >> j) & 1ULL)) local |= dj;
      }
      if (lane == 0) { rem[c] = local; aliveSh = ~local; }
    }
    __syncthreads();
    u64 alive = aliveSh;
    int nw = NWORDS - 1 - c;
    if (nw > 0 && alive) {
      int npairs = 64 * nw;
      for (int p = t; p < npairs; p += 1024) {
        int j = p / nw;
        int w = c + 1 + (p - j * nw);
        if ((alive >> j) & 1ULL) {
          int i = c * 64 + j;
          if (i < TOPN) {
            u64 v = mask[(size_t)i * NWORDS + w];
            if (v) atomicOr(&rem[w], v);
          }
        }
      }
    }
    __syncthreads();
  }
  // ranked scatter of first 2000 kept boxes
  if (t == 0) {
    int s = 0;
    for (int w = 0; w < NWORDS; ++w) { pref[w] = s; s += __popcll(~rem[w]); }
    pref[NWORDS] = s;
  }
  __syncthreads();
  for (int i = t; i < TOPN; i += 1024) {
    u64 kw = ~rem[i >> 6];
    if ((kw >> (i & 63)) & 1ULL) {
      int rank = pref[i >> 6] + __popcll(kw & ((1ULL << (i & 63)) - 1ULL));
      if (rank < NOUT) {
        out[rank * 4 + 0] = (float)boxes[i * 4 + 0];
        out[rank * 4 + 1] = (float)boxes[i * 4 + 1];
        out[rank * 4 + 2] = (float)boxes[i * 4 + 2];
        out[rank * 4 + 3] = (float)boxes[i * 4 + 3];
      }
    }
  }
}

extern "C" void kernel_launch(void* const* d_in, const int* in_sizes, int n_in,
                              void* d_out, int out_size, void* d_ws, size_t ws_size,
                              hipStream_t stream) {
  const float* feat = (const float*)d_in[0];
  const float* c3w = (const float*)d_in[1];
  const float* c3b = (const float*)d_in[2];
  const float* clw = (const float*)d_in[3];
  const float* clb = (const float*)d_in[4];
  const float* rgw = (const float*)d_in[5];
  const float* rgb = (const float*)d_in[6];
  float* out = (float*)d_out;
  char* ws = (char*)d_ws;
  size_t off = 0;
  auto alloc = [&](size_t bytes) {
    size_t o = off;
    off = (off + bytes + 255) & ~(size_t)255;
    return o;
  };
  double* predacc = (double*)(ws + alloc(16384ULL * 54 * 8));     // 7.08 MB
  float* wt = (float*)(ws + alloc(2359296ULL * 4));               // 9.44 MB
  double* roi_all = (double*)(ws + alloc((size_t)NANC * 4 * 8));  // 4.72 MB
  double* scores_d = (double*)(ws + alloc((size_t)NANC * 8));     // 1.18 MB
  ulonglong2* sortb = (ulonglong2*)(ws + alloc((size_t)NSORT * 16)); // 4.19 MB
  double* boxes = (double*)(ws + alloc((size_t)TOPN * 4 * 8));    // 0.19 MB
  u64* mask = (u64*)(ws + alloc((size_t)TOPN * NWORDS * 8));      // 4.51 MB
  u64* removed = (u64*)(ws + alloc(NWORDS * 8));
  unsigned* hist = (unsigned*)(ws + alloc(2048 * 4));             // 8 KB
  u64* selp = (u64*)(ws + alloc(256));
  unsigned* cntb = (unsigned*)(ws + alloc(256));
  ulonglong2* cand = (ulonglong2*)(ws + alloc((size_t)NCAND * 16));   // 128 KB
  ulonglong2* bcand = (ulonglong2*)(ws + alloc((size_t)NBCAP * 16));  // 32 KB
  (void)ws_size; (void)out_size; (void)in_sizes; (void)n_in;

  const int NPRED = 16384 * 54;
  hipLaunchKernelGGL(zinit_k, dim3((NPRED + 255) / 256), dim3(256), 0, stream,
                     predacc, NPRED, hist, selp, cntb);
  hipLaunchKernelGGL(wtrans_k, dim3(512), dim3(256), 0, stream, c3w, wt);
  hipLaunchKernelGGL(conv_mfma_k, dim3(2048), dim3(256), 0, stream,
                     feat, wt, c3b, clw, rgw, predacc);
  hipLaunchKernelGGL(anchor_k, dim3(NSORT / 256), dim3(256), 0, stream,
                     predacc, clb, rgb, out, roi_all, scores_d, sortb);
  // radix-select top-6000
  for (int pass = 0; pass < 3; ++pass) {
    hipLaunchKernelGGL(hist_k, dim3(128), dim3(1024), 0, stream,
                       sortb, hist, selp, pass);
    hipLaunchKernelGGL(scan_k, dim3(1), dim3(1024), 0, stream, hist, selp, pass);
  }
  hipLaunchKernelGGL(compact_k, dim3(128), dim3(1024), 0, stream,
                     sortb, selp, cand, bcand, cntb);
  // parallel bitonic sort of 8192 candidates (4-block local + merges)
  hipLaunchKernelGGL(sortloc_k, dim3(4), dim3(1024), 0, stream,
                     cand, bcand, cntb);
  hipLaunchKernelGGL(bitonic_global, dim3(NCAND / 512), dim3(256), 0, stream,
                     cand, 4096, 2048);
  hipLaunchKernelGGL(bitonic_lm, dim3(4), dim3(1024), 0, stream, cand, 4096);
  hipLaunchKernelGGL(bitonic_global, dim3(NCAND / 512), dim3(256), 0, stream,
                     cand, 8192, 4096);
  hipLaunchKernelGGL(bitonic_global, dim3(NCAND / 512), dim3(256), 0, stream,
                     cand, 8192, 2048);
  hipLaunchKernelGGL(sortfin_k, dim3(4), dim3(1024), 0, stream,
                     cand, roi_all, scores_d, boxes, removed);
  // NMS + output
  hipLaunchKernelGGL(mask_k, dim3(TOPN * NWORDS / 4), dim3(256), 0, stream,
                     boxes, mask);
  hipLaunchKernelGGL(nmsout_k, dim3(1), dim3(1024), 0, stream,
                     mask, removed, boxes, out);
}